// Round 3
// baseline (1331.223 us; speedup 1.0000x reference)
//
#include <hip/hip_runtime.h>
#include <hip/hip_bf16.h>
#include <hip/hip_fp16.h>

typedef __hip_bfloat16 bf16;

constexpr int kB  = 128;
constexpr int kS  = 512;
constexpr int kT  = 64;
constexpr int kD  = 48;
constexpr int kFF = 128;
constexpr int kNH = 4;
constexpr int kHD = 12;

__device__ __forceinline__ float b2f(bf16 v){ return __bfloat162float(v); }

// dual-mode input load: f32!=0 -> buffer holds fp32, else bf16
__device__ __forceinline__ float ldin(const void* p, int i, int f32){
  return f32 ? ((const float*)p)[i] : __bfloat162float(((const bf16*)p)[i]);
}

// pe[p, 2i] = sin(p * exp(-2i*ln(10000)/48)), pe[p, 2i+1] = cos(...)
__device__ __forceinline__ float pe_val(int p, int j){
  int i = j >> 1;
  float f = expf(-0.19188209108283716f * (float)(2*i));
  float a = (float)p * f;
  return (j & 1) ? cosf(a) : sinf(a);
}

// ---------------- K-1: dtype detector ----------------
// If src is fp32 read as uint16, even halves are mantissa bits -> bf16 exponents
// >= 0x90 (2^17) appear w.p. ~1. Genuine bf16 N(0,1) caps at exponent ~0x81.
__global__ void k_detect(const unsigned short* __restrict__ s, int n, int* __restrict__ flag){
  int ev = 0;
  for (int i = threadIdx.x; i < n; i += 256){
    int e = (s[i] >> 7) & 0xFF;
    if (e >= 0x90) ev = 1;
  }
  unsigned long long b = __ballot(ev != 0);
  __shared__ int sh[4];
  if ((threadIdx.x & 63) == 0) sh[threadIdx.x >> 6] = (b != 0ull) ? 1 : 0;
  __syncthreads();
  if (threadIdx.x == 0) flag[0] = sh[0] | sh[1] | sh[2] | sh[3];
}

// ---------------- K1: embed + PE -> X0 (fp32) ----------------
__global__ void k_embed(const void* __restrict__ src, const void* __restrict__ in_w,
                        const void* __restrict__ in_b, const int* __restrict__ flag,
                        float* __restrict__ X0){
  int f32 = flag[0];
  int idx = blockIdx.x*256 + threadIdx.x;
  if (idx >= kB*kS*kD) return;
  int j = idx % kD; int bs = idx / kD; int s = bs % kS;
  float v = (ldin(src,bs,f32) * ldin(in_w,j,f32) + ldin(in_b,j,f32)) * 6.928203230275509f;
  X0[idx] = v + pe_val(s, j);
}

// ---------------- K2: encoder QKV projection (fp16 outputs) ----------------
__global__ void __launch_bounds__(256) k_qkv(const float* __restrict__ X,
    const void* __restrict__ wq, const void* __restrict__ bq,
    const void* __restrict__ wk, const void* __restrict__ bk,
    const void* __restrict__ wv, const void* __restrict__ bv,
    const int* __restrict__ flag,
    __half* __restrict__ Q, __half* __restrict__ K, __half* __restrict__ V){
  int f32 = flag[0];
  __shared__ __align__(16) float W[3][kD*kD];
  __shared__ __align__(16) float bias[3][kD];
  __shared__ __align__(16) float xt[32][kD];
  int tid = threadIdx.x;
  for (int i=tid;i<3*kD*kD;i+=256){ int m=i/(kD*kD), e=i%(kD*kD);
    const void* w = (m==0)?wq:((m==1)?wk:wv); W[m][e]=ldin(w,e,f32); }
  for (int i=tid;i<3*kD;i+=256){ int m=i/kD,e=i%kD;
    const void* w=(m==0)?bq:((m==1)?bk:bv); bias[m][e]=ldin(w,e,f32); }
  long row0 = (long)blockIdx.x*32;
  for (int i=tid;i<32*kD;i+=256) xt[i/kD][i%kD] = X[row0*kD + i];
  __syncthreads();
  for (int i=tid;i<32*3*kD;i+=256){
    int r=i/(3*kD), c=i%(3*kD), m=c/kD, j=c%kD;
    float acc=bias[m][j];
    #pragma unroll
    for(int k=0;k<kD;k++) acc += xt[r][k]*W[m][k*kD+j];
    __half* o = (m==0)?Q:((m==1)?K:V);
    o[(row0+r)*kD+j]=__float2half(acc);
  }
}

// ---------------- K3: encoder attention, one block per (b,h) ----------------
// NOTE: O aliases Q (in-place, per-block column slice) -> no __restrict__.
__global__ void __launch_bounds__(256) k_attn(const __half* Q, const __half* __restrict__ K,
                       const __half* __restrict__ V, __half* O){
  int b = blockIdx.x / kNH, h = blockIdx.x % kNH;
  __shared__ __align__(16) float Qs[kS*kHD];
  __shared__ __align__(16) float Ks[kS*kHD];
  __shared__ __align__(16) float Vs[kS*kHD];
  int tid = threadIdx.x;
  long base = ((long)b*kS)*kD + h*kHD;
  for (int i=tid;i<kS*kHD;i+=256){ int r=i/kHD, j=i%kHD;
    long g = base + (long)r*kD + j;
    Qs[i]=__half2float(Q[g]); Ks[i]=__half2float(K[g]); Vs[i]=__half2float(V[g]); }
  __syncthreads();
  const float rs = 0.28867513459481287f;
  int q0 = tid, q1 = tid+256;
  float qa[kHD], qb[kHD];
  #pragma unroll
  for(int j=0;j<kHD;j++){ qa[j]=Qs[q0*kHD+j]; qb[j]=Qs[q1*kHD+j]; }
  float acc0[kHD], acc1[kHD];
  #pragma unroll
  for(int j=0;j<kHD;j++){ acc0[j]=0.f; acc1[j]=0.f; }
  float l0=0.f, l1=0.f, m0=-1e30f, m1=-1e30f;
  for(int k=0;k<kS;k++){
    const float4* kp=(const float4*)(Ks+k*kHD);
    const float4* vp=(const float4*)(Vs+k*kHD);
    float4 ka=kp[0], kb4=kp[1], kc4=kp[2];
    float kr[kHD]={ka.x,ka.y,ka.z,ka.w,kb4.x,kb4.y,kb4.z,kb4.w,kc4.x,kc4.y,kc4.z,kc4.w};
    float s0=0.f,s1=0.f;
    #pragma unroll
    for(int j=0;j<kHD;j++){ s0+=qa[j]*kr[j]; s1+=qb[j]*kr[j]; }
    s0*=rs; s1*=rs;
    if(s0>m0){ float c=__expf(m0-s0); l0*=c;
      #pragma unroll
      for(int j=0;j<kHD;j++) acc0[j]*=c;
      m0=s0; }
    if(s1>m1){ float c=__expf(m1-s1); l1*=c;
      #pragma unroll
      for(int j=0;j<kHD;j++) acc1[j]*=c;
      m1=s1; }
    float p0=__expf(s0-m0), p1=__expf(s1-m1);
    l0+=p0; l1+=p1;
    float4 va=vp[0], vb4=vp[1], vc4=vp[2];
    float vr[kHD]={va.x,va.y,va.z,va.w,vb4.x,vb4.y,vb4.z,vb4.w,vc4.x,vc4.y,vc4.z,vc4.w};
    #pragma unroll
    for(int j=0;j<kHD;j++){ acc0[j]+=p0*vr[j]; acc1[j]+=p1*vr[j]; }
  }
  float i0=1.f/l0, i1=1.f/l1;
  #pragma unroll
  for(int j=0;j<kHD;j++){
    O[base+(long)q0*kD+j]=__float2half(acc0[j]*i0);
    O[base+(long)q1*kD+j]=__float2half(acc1[j]*i1);
  }
}

// ---------------- K4: o-proj + residual + LN (fp16 out) ----------------
__global__ void __launch_bounds__(256) k_oproj_ln(const float* __restrict__ Xres, const __half* __restrict__ O,
      const void* __restrict__ wo, const void* __restrict__ bo,
      const void* __restrict__ g, const void* __restrict__ bb,
      const int* __restrict__ flag, __half* __restrict__ Xout){
  int f32 = flag[0];
  __shared__ __align__(16) float W[kD*kD];
  __shared__ float bsh[kD], gs[kD], bs2[kD];
  __shared__ __align__(16) float res[32][kD];
  __shared__ __align__(16) float ot[32][kD];
  __shared__ float mrow[32], rstd[32];
  int tid=threadIdx.x;
  for(int i=tid;i<kD*kD;i+=256) W[i]=ldin(wo,i,f32);
  if(tid<kD){ bsh[tid]=ldin(bo,tid,f32); gs[tid]=ldin(g,tid,f32); bs2[tid]=ldin(bb,tid,f32); }
  long row0=(long)blockIdx.x*32;
  for(int i=tid;i<32*kD;i+=256) ot[i/kD][i%kD]=__half2float(O[row0*kD+i]);
  __syncthreads();
  for(int i=tid;i<32*kD;i+=256){ int r=i/kD,j=i%kD;
    float acc=bsh[j];
    #pragma unroll
    for(int k=0;k<kD;k++) acc+=ot[r][k]*W[k*kD+j];
    res[r][j]=Xres[row0*kD+i]+acc;
  }
  __syncthreads();
  if(tid<32){
    float s=0.f;
    for(int j=0;j<kD;j++) s+=res[tid][j];
    float m=s*(1.f/kD); float v=0.f;
    for(int j=0;j<kD;j++){float d=res[tid][j]-m; v+=d*d;}
    mrow[tid]=m; rstd[tid]=rsqrtf(v*(1.f/kD)+1e-5f);
  }
  __syncthreads();
  for(int i=tid;i<32*kD;i+=256){int r=i/kD,j=i%kD;
    Xout[row0*kD+i]=__float2half((res[r][j]-mrow[r])*rstd[r]*gs[j]+bs2[j]); }
}

// ---------------- K5: FFN + residual + LN (fp16 in, fp32 out) ----------------
__global__ void __launch_bounds__(256) k_ffn_ln(const __half* __restrict__ Xin,
   const void* __restrict__ w1, const void* __restrict__ b1,
   const void* __restrict__ w2, const void* __restrict__ b2,
   const void* __restrict__ g, const void* __restrict__ bb,
   const int* __restrict__ flag, float* __restrict__ Xout){
  int f32 = flag[0];
  __shared__ __align__(16) float W1[kD*kFF];
  __shared__ __align__(16) float W2[kFF*kD];
  __shared__ float b1s[kFF], b2s[kD], gs[kD], bs2[kD];
  __shared__ __align__(16) float xt[16][kD];
  __shared__ __align__(16) float h1[16][kFF];
  __shared__ __align__(16) float res[16][kD];
  __shared__ float mrow[16], rstd[16];
  int tid=threadIdx.x;
  for(int i=tid;i<kD*kFF;i+=256) W1[i]=ldin(w1,i,f32);
  for(int i=tid;i<kFF*kD;i+=256) W2[i]=ldin(w2,i,f32);
  if(tid<kFF) b1s[tid]=ldin(b1,tid,f32);
  if(tid<kD){ b2s[tid]=ldin(b2,tid,f32); gs[tid]=ldin(g,tid,f32); bs2[tid]=ldin(bb,tid,f32); }
  long row0=(long)blockIdx.x*16;
  for(int i=tid;i<16*kD;i+=256) xt[i/kD][i%kD]=__half2float(Xin[row0*kD+i]);
  __syncthreads();
  for(int i=tid;i<16*kFF;i+=256){int r=i/kFF,c=i%kFF;
    float acc=b1s[c];
    #pragma unroll
    for(int k=0;k<kD;k++) acc+=xt[r][k]*W1[k*kFF+c];
    h1[r][c]=fmaxf(acc,0.f);}
  __syncthreads();
  for(int i=tid;i<16*kD;i+=256){int r=i/kD,j=i%kD;
    float acc=b2s[j];
    #pragma unroll
    for(int k=0;k<kFF;k++) acc+=h1[r][k]*W2[k*kD+j];
    res[r][j]=xt[r][j]+acc;}
  __syncthreads();
  if(tid<16){
    float s=0.f;
    for(int j=0;j<kD;j++) s+=res[tid][j];
    float m=s*(1.f/kD); float v=0.f;
    for(int j=0;j<kD;j++){float d=res[tid][j]-m; v+=d*d;}
    mrow[tid]=m; rstd[tid]=rsqrtf(v*(1.f/kD)+1e-5f);
  }
  __syncthreads();
  for(int i=tid;i<16*kD;i+=256){int r=i/kD,j=i%kD;
    Xout[row0*kD+i]=(res[r][j]-mrow[r])*rstd[r]*gs[j]+bs2[j]; }
}

// ---------------- K6: cross K/V projection from mem (fp16 out) ----------------
__global__ void __launch_bounds__(256) k_ckv(const float* __restrict__ M,
    const void* __restrict__ wk, const void* __restrict__ bk,
    const void* __restrict__ wv, const void* __restrict__ bv,
    const int* __restrict__ flag,
    __half* __restrict__ Kc, __half* __restrict__ Vc){
  int f32 = flag[0];
  __shared__ __align__(16) float W[2][kD*kD];
  __shared__ float bias[2][kD];
  __shared__ __align__(16) float xt[32][kD];
  int tid=threadIdx.x;
  for(int i=tid;i<2*kD*kD;i+=256){int m=i/(kD*kD),e=i%(kD*kD);
    const void* w=m?wv:wk; W[m][e]=ldin(w,e,f32);}
  for(int i=tid;i<2*kD;i+=256){int m=i/kD,e=i%kD; const void* w=m?bv:bk; bias[m][e]=ldin(w,e,f32);}
  long row0=(long)blockIdx.x*32;
  for(int i=tid;i<32*kD;i+=256) xt[i/kD][i%kD]=M[row0*kD+i];
  __syncthreads();
  for(int i=tid;i<32*2*kD;i+=256){
    int r=i/(2*kD), c=i%(2*kD), m=c/kD, j=c%kD;
    float acc=bias[m][j];
    #pragma unroll
    for(int k=0;k<kD;k++) acc+=xt[r][k]*W[m][k*kD+j];
    (m?Vc:Kc)[(row0+r)*kD+j]=__float2half(acc);
  }
}

// ---------------- K0: transpose+convert decoder weights to fp32 ----------------
// Wd floats: swqT@0, swkT@2304, swvT@4608, swoT@6912, cwqT@9216, cwoT@11520,
// w1T@13824 (kFF x kD), w2T@19968 (kD x kFF). Total 26112.
__global__ void k_prep(const void* __restrict__ swq,const void* __restrict__ swk,
                       const void* __restrict__ swv,const void* __restrict__ swo,
                       const void* __restrict__ cwq,const void* __restrict__ cwo,
                       const void* __restrict__ w1,const void* __restrict__ w2,
                       const int* __restrict__ flag, float* __restrict__ Wd){
  int f32 = flag[0];
  int idx=blockIdx.x*256+threadIdx.x;
  if(idx>=26112) return;
  float v;
  if(idx<2304){int e=idx;        int j=e/48,i=e%48; v=ldin(swq,i*48+j,f32);}
  else if(idx<4608){int e=idx-2304; int j=e/48,i=e%48; v=ldin(swk,i*48+j,f32);}
  else if(idx<6912){int e=idx-4608; int j=e/48,i=e%48; v=ldin(swv,i*48+j,f32);}
  else if(idx<9216){int e=idx-6912; int j=e/48,i=e%48; v=ldin(swo,i*48+j,f32);}
  else if(idx<11520){int e=idx-9216; int j=e/48,i=e%48; v=ldin(cwq,i*48+j,f32);}
  else if(idx<13824){int e=idx-11520;int j=e/48,i=e%48; v=ldin(cwo,i*48+j,f32);}
  else if(idx<19968){int e=idx-13824;int c=e/48,i=e%48; v=ldin(w1,i*128+c,f32);}
  else              {int e=idx-19968;int j=e/128,c=e%128; v=ldin(w2,c*48+j,f32);}
  Wd[idx]=v;
}

// ---------------- K7: full decoder, one block per batch element ----------------
struct DecP {
  const void *dec_start, *sbq, *sbk, *sbv, *sbo, *ln1g, *ln1b,
             *cbq, *cbo, *ln2g, *ln2b, *fb1, *fb2, *ln3g, *ln3b, *ow, *ob;
};

__device__ __forceinline__ void ln48(const float* in, float* out,
                                     const void* g, const void* b,
                                     int tid, float* red2, int f32){
  if(tid<64){
    float v=(tid<kD)?in[tid]:0.f;
    float s=v;
    #pragma unroll
    for(int o=32;o>=1;o>>=1) s+=__shfl_xor(s,o,64);
    float mean=s*(1.f/kD);
    float d=(tid<kD)?(v-mean):0.f;
    float s2=d*d;
    #pragma unroll
    for(int o=32;o>=1;o>>=1) s2+=__shfl_xor(s2,o,64);
    if(tid==0){ red2[0]=mean; red2[1]=rsqrtf(s2*(1.f/kD)+1e-5f); }
  }
  __syncthreads();
  if(tid<kD) out[tid]=(in[tid]-red2[0])*red2[1]*ldin(g,tid,f32)+ldin(b,tid,f32);
  __syncthreads();
}

__global__ void __launch_bounds__(256) k_dec(const __half* __restrict__ Kc, const __half* __restrict__ Vc,
    const float* __restrict__ Wd, DecP P, const int* __restrict__ flag, void* __restrict__ out){
  __shared__ __align__(16) __half KcL[kS*kD];   // 49152 B
  __shared__ __align__(16) __half VcL[kS*kD];   // 49152 B
  __shared__ __align__(16) float Ksl[(kT+1)*kD];
  __shared__ __align__(16) float Vsl[(kT+1)*kD];
  __shared__ __align__(16) float sc[kNH*64];
  __shared__ __align__(16) float xv[kD];
  __shared__ __align__(16) float qv[kD];
  __shared__ __align__(16) float so[kD];
  __shared__ __align__(16) float h1[kD];
  __shared__ __align__(16) float cq[kD];
  __shared__ __align__(16) float cov[kD];
  __shared__ __align__(16) float h2[kD];
  __shared__ __align__(16) float f1[kFF];
  __shared__ __align__(16) float rr[kD];
  __shared__ __align__(16) float cur[kD];
  __shared__ float ssum[kNH], red2[2];
  int tid=threadIdx.x, b=blockIdx.x;
  int f32 = flag[0];
  int wave=tid>>6, lane=tid&63;
  const float rs = 0.28867513459481287f;

  long cb=(long)b*kS*kD;
  { const uint2* ks=(const uint2*)(Kc+cb); const uint2* vs=(const uint2*)(Vc+cb);
    uint2* kd=(uint2*)KcL; uint2* vd=(uint2*)VcL;
    for(int i=tid;i<kS*kD/4;i+=256){ kd[i]=ks[i]; vd[i]=vs[i]; } }
  if(tid<kD) cur[tid]=ldin(P.dec_start,tid,f32);
  __syncthreads();

  for(int t=0;t<kT;t++){
    if(tid<kD) xv[tid]=cur[tid]+pe_val(t,tid);
    __syncthreads();
    // self q/k/v projections (144 threads)
    if(tid<3*kD){
      int m=tid/kD, j=tid%kD;
      const void* bp = (m==0)?P.sbq:((m==1)?P.sbk:P.sbv);
      float acc=ldin(bp,j,f32);
      const float4* w=(const float4*)(Wd + m*2304 + j*48);
      #pragma unroll
      for(int k=0;k<12;k++){ float4 w4=w[k];
        acc+=xv[4*k]*w4.x+xv[4*k+1]*w4.y+xv[4*k+2]*w4.z+xv[4*k+3]*w4.w; }
      if(m==0) qv[j]=acc; else if(m==1) Ksl[t*kD+j]=acc; else Vsl[t*kD+j]=acc;
    }
    __syncthreads();
    // self attention: wave = head, lane = key (L <= 64)
    {
      int L=t+1;
      float qh[kHD];
      #pragma unroll
      for(int j=0;j<kHD;j++) qh[j]=qv[wave*kHD+j];
      float s=-1e30f;
      if(lane<L){
        const float4* kp=(const float4*)(Ksl + lane*kD + wave*kHD);
        float4 a=kp[0],b4=kp[1],c4=kp[2];
        s = qh[0]*a.x+qh[1]*a.y+qh[2]*a.z+qh[3]*a.w
           +qh[4]*b4.x+qh[5]*b4.y+qh[6]*b4.z+qh[7]*b4.w
           +qh[8]*c4.x+qh[9]*c4.y+qh[10]*c4.z+qh[11]*c4.w;
        s*=rs;
      }
      float m=s;
      #pragma unroll
      for(int o=32;o>=1;o>>=1) m=fmaxf(m,__shfl_xor(m,o,64));
      float p=(lane<L)?__expf(s-m):0.f;
      float l=p;
      #pragma unroll
      for(int o=32;o>=1;o>>=1) l+=__shfl_xor(l,o,64);
      sc[wave*64+lane]=p;
      if(lane==0) ssum[wave]=l;
    }
    __syncthreads();
    if(tid<kD){
      int h=tid/kHD;
      float acc=0.f;
      for(int k=0;k<=t;k++) acc+=sc[h*64+k]*Vsl[k*kD+tid];
      so[tid]=acc/ssum[h];
    }
    __syncthreads();
    // self o-proj + residual
    if(tid<kD){
      float acc=ldin(P.sbo,tid,f32);
      const float4* w=(const float4*)(Wd + 6912 + tid*48);
      #pragma unroll
      for(int k=0;k<12;k++){ float4 w4=w[k];
        acc+=so[4*k]*w4.x+so[4*k+1]*w4.y+so[4*k+2]*w4.z+so[4*k+3]*w4.w; }
      rr[tid]=xv[tid]+acc;
    }
    __syncthreads();
    ln48(rr,h1,P.ln1g,P.ln1b,tid,red2,f32);
    // cross q projection
    if(tid<kD){
      float acc=ldin(P.cbq,tid,f32);
      const float4* w=(const float4*)(Wd + 9216 + tid*48);
      #pragma unroll
      for(int k=0;k<12;k++){ float4 w4=w[k];
        acc+=h1[4*k]*w4.x+h1[4*k+1]*w4.y+h1[4*k+2]*w4.z+h1[4*k+3]*w4.w; }
      cq[tid]=acc;
    }
    __syncthreads();
    // cross attention over 512 keys: wave = head, 8 keys/lane
    {
      float qh[kHD];
      #pragma unroll
      for(int j=0;j<kHD;j++) qh[j]=cq[wave*kHD+j];
      float sv[8]; float mx=-1e30f;
      #pragma unroll
      for(int i=0;i<8;i++){
        int k=lane+64*i;
        const __half2* kp=(const __half2*)(KcL + k*kD + wave*kHD);
        float s=0.f;
        #pragma unroll
        for(int u=0;u<6;u++){ float2 kv=__half22float2(kp[u]); s+=qh[2*u]*kv.x+qh[2*u+1]*kv.y; }
        sv[i]=s*rs;
        mx=fmaxf(mx,sv[i]);
      }
      #pragma unroll
      for(int o=32;o>=1;o>>=1) mx=fmaxf(mx,__shfl_xor(mx,o,64));
      float p8[8]; float l=0.f;
      #pragma unroll
      for(int i=0;i<8;i++){ p8[i]=__expf(sv[i]-mx); l+=p8[i]; }
      #pragma unroll
      for(int o=32;o>=1;o>>=1) l+=__shfl_xor(l,o,64);
      float inv=1.f/l;
      float acc[kHD];
      #pragma unroll
      for(int j=0;j<kHD;j++) acc[j]=0.f;
      #pragma unroll
      for(int i=0;i<8;i++){
        int k=lane+64*i;
        const __half2* vp=(const __half2*)(VcL + k*kD + wave*kHD);
        #pragma unroll
        for(int u=0;u<6;u++){ float2 vv=__half22float2(vp[u]);
          acc[2*u]+=p8[i]*vv.x; acc[2*u+1]+=p8[i]*vv.y; }
      }
      #pragma unroll
      for(int j=0;j<kHD;j++){
        #pragma unroll
        for(int o=32;o>=1;o>>=1) acc[j]+=__shfl_xor(acc[j],o,64);
      }
      if(lane==0){
        #pragma unroll
        for(int j=0;j<kHD;j++) cov[wave*kHD+j]=acc[j]*inv;
      }
    }
    __syncthreads();
    // cross o-proj + residual
    if(tid<kD){
      float acc=ldin(P.cbo,tid,f32);
      const float4* w=(const float4*)(Wd + 11520 + tid*48);
      #pragma unroll
      for(int k=0;k<12;k++){ float4 w4=w[k];
        acc+=cov[4*k]*w4.x+cov[4*k+1]*w4.y+cov[4*k+2]*w4.z+cov[4*k+3]*w4.w; }
      rr[tid]=h1[tid]+acc;
    }
    __syncthreads();
    ln48(rr,h2,P.ln2g,P.ln2b,tid,red2,f32);
    // FFN
    if(tid<kFF){
      float acc=ldin(P.fb1,tid,f32);
      const float4* w=(const float4*)(Wd + 13824 + tid*48);
      #pragma unroll
      for(int k=0;k<12;k++){ float4 w4=w[k];
        acc+=h2[4*k]*w4.x+h2[4*k+1]*w4.y+h2[4*k+2]*w4.z+h2[4*k+3]*w4.w; }
      f1[tid]=fmaxf(acc,0.f);
    }
    __syncthreads();
    if(tid<kD){
      float acc=ldin(P.fb2,tid,f32);
      const float4* w=(const float4*)(Wd + 19968 + tid*128);
      #pragma unroll
      for(int k=0;k<32;k++){ float4 w4=w[k];
        acc+=f1[4*k]*w4.x+f1[4*k+1]*w4.y+f1[4*k+2]*w4.z+f1[4*k+3]*w4.w; }
      rr[tid]=h2[tid]+acc;
    }
    __syncthreads();
    ln48(rr,cur,P.ln3g,P.ln3b,tid,red2,f32);
    // y[b,t] = cur . out_w + out_b
    if(tid<64){
      float v=(tid<kD)?cur[tid]*ldin(P.ow,tid,f32):0.f;
      #pragma unroll
      for(int o=32;o>=1;o>>=1) v+=__shfl_xor(v,o,64);
      if(tid==0){
        float y=v+ldin(P.ob,0,f32);
        if(f32) ((float*)out)[b*kT+t]=y;
        else    ((bf16*)out)[b*kT+t]=__float2bfloat16(y);
      }
    }
    __syncthreads();
  }
}

extern "C" void kernel_launch(void* const* d_in, const int* in_sizes, int n_in,
                              void* d_out, int out_size, void* d_ws, size_t ws_size,
                              hipStream_t stream){
  // workspace layout (total ~30.1 MiB):
  //   Wd:   ws[0..26112) fp32 decoder weights (reserve 32768 floats; flag at +26112)
  //   A:    fp32 buffer, kB*kS*kD floats (x, then mem)
  //   H1:   fp16 buffer (Q -> attnO -> crossK)
  //   H2:   fp16 buffer (K -> ln1 out)
  //   H3:   fp16 buffer (V -> crossV)
  float* ws = (float*)d_ws;
  float* Wd = ws;
  int*   flag = (int*)(ws + 26112);
  const size_t NB = (size_t)kB*kS*kD;     // 3,145,728
  float*  A  = ws + 32768;
  __half* H1 = (__half*)(A + NB);
  __half* H2 = H1 + NB;
  __half* H3 = H2 + NB;

  k_detect<<<1,256,0,stream>>>((const unsigned short*)d_in[0], kB*kS, flag);
  k_embed<<<(kB*kS*kD+255)/256,256,0,stream>>>(d_in[0],d_in[1],d_in[2],flag,A);
  k_qkv  <<<(kB*kS)/32,256,0,stream>>>(A,d_in[4],d_in[5],d_in[6],d_in[7],d_in[8],d_in[9],flag,H1,H2,H3);
  k_attn <<<kB*kNH,256,0,stream>>>(H1,H2,H3,H1);
  k_oproj_ln<<<(kB*kS)/32,256,0,stream>>>(A,H1,d_in[10],d_in[11],d_in[12],d_in[13],flag,H2);
  k_ffn_ln  <<<(kB*kS)/16,256,0,stream>>>(H2,d_in[14],d_in[15],d_in[16],d_in[17],d_in[18],d_in[19],flag,A);
  k_ckv     <<<(kB*kS)/32,256,0,stream>>>(A,d_in[32],d_in[33],d_in[34],d_in[35],flag,H1,H3);
  k_prep    <<<(26112+255)/256,256,0,stream>>>(d_in[20],d_in[22],d_in[24],d_in[26],d_in[30],d_in[36],d_in[40],d_in[42],flag,Wd);

  DecP P;
  P.dec_start=d_in[3];
  P.sbq=d_in[21]; P.sbk=d_in[23]; P.sbv=d_in[25]; P.sbo=d_in[27];
  P.ln1g=d_in[28]; P.ln1b=d_in[29];
  P.cbq=d_in[31]; P.cbo=d_in[37];
  P.ln2g=d_in[38]; P.ln2b=d_in[39];
  P.fb1=d_in[41]; P.fb2=d_in[43];
  P.ln3g=d_in[44]; P.ln3b=d_in[45];
  P.ow=d_in[46]; P.ob=d_in[47];
  k_dec<<<kB,256,0,stream>>>(H1,H3,Wd,P,flag,(void*)d_out);
}

// Round 6
// 1125.936 us; speedup vs baseline: 1.1823x; 1.1823x over previous
//
#include <hip/hip_runtime.h>
#include <hip/hip_bf16.h>
#include <hip/hip_fp16.h>

// NOTE (verified R3/R5): harness inputs are FP32 (reference is jnp.float32),
// output is FP32. Reading inputs as bf16 produces NaN weights — R4/R5's bug.

constexpr int kB  = 128;
constexpr int kS  = 512;
constexpr int kT  = 64;
constexpr int kD  = 48;
constexpr int kFF = 128;
constexpr int kNH = 4;
constexpr int kHD = 12;

__device__ __forceinline__ float wsum(float v){
  #pragma unroll
  for(int o=32;o>=1;o>>=1) v += __shfl_xor(v,o,64);
  return v;
}
__device__ __forceinline__ float wmax(float v){
  #pragma unroll
  for(int o=32;o>=1;o>>=1) v = fmaxf(v,__shfl_xor(v,o,64));
  return v;
}

// pe[p, 2i] = sin(p * exp(-2i*ln(10000)/48)), pe[p, 2i+1] = cos(...)
__device__ __forceinline__ float pe_val(int p, int j){
  int i = j >> 1;
  float f = expf(-0.19188209108283716f * (float)(2*i));
  float a = (float)p * f;
  return (j & 1) ? cosf(a) : sinf(a);
}

// ---------------- K1: embed + PE -> X0 (fp32) ----------------
__global__ void k_embed(const float* __restrict__ src, const float* __restrict__ in_w,
                        const float* __restrict__ in_b, float* __restrict__ X0){
  int idx = blockIdx.x*256 + threadIdx.x;
  if (idx >= kB*kS*kD) return;
  int j = idx % kD; int bs = idx / kD; int s = bs % kS;
  float v = (src[bs] * in_w[j] + in_b[j]) * 6.928203230275509f;
  X0[idx] = v + pe_val(s, j);
}

// ---------------- K2: encoder QKV projection (fp16 outputs) ----------------
__global__ void __launch_bounds__(256) k_qkv(const float* __restrict__ X,
    const float* __restrict__ wq, const float* __restrict__ bq,
    const float* __restrict__ wk, const float* __restrict__ bk,
    const float* __restrict__ wv, const float* __restrict__ bv,
    __half* __restrict__ Q, __half* __restrict__ K, __half* __restrict__ V){
  __shared__ __align__(16) float W[3][kD*kD];
  __shared__ __align__(16) float bias[3][kD];
  __shared__ __align__(16) float xt[32][kD];
  int tid = threadIdx.x;
  for (int i=tid;i<3*kD*kD;i+=256){ int m=i/(kD*kD), e=i%(kD*kD);
    const float* w = (m==0)?wq:((m==1)?wk:wv); W[m][e]=w[e]; }
  for (int i=tid;i<3*kD;i+=256){ int m=i/kD,e=i%kD;
    const float* w=(m==0)?bq:((m==1)?bk:bv); bias[m][e]=w[e]; }
  long row0 = (long)blockIdx.x*32;
  for (int i=tid;i<32*kD;i+=256) xt[i/kD][i%kD] = X[row0*kD + i];
  __syncthreads();
  for (int i=tid;i<32*3*kD;i+=256){
    int r=i/(3*kD), c=i%(3*kD), m=c/kD, j=c%kD;
    float acc=bias[m][j];
    #pragma unroll
    for(int k=0;k<kD;k++) acc += xt[r][k]*W[m][k*kD+j];
    __half* o = (m==0)?Q:((m==1)?K:V);
    o[(row0+r)*kD+j]=__float2half(acc);
  }
}

// ---------------- K3: encoder attention (R3-exact structure) ----------------
__global__ void __launch_bounds__(256) k_attn(const __half* Q, const __half* __restrict__ K,
                       const __half* __restrict__ V, __half* O){
  int b = blockIdx.x / kNH, h = blockIdx.x % kNH;
  __shared__ __align__(16) float Qs[kS*kHD];
  __shared__ __align__(16) float Ks[kS*kHD];
  __shared__ __align__(16) float Vs[kS*kHD];
  int tid = threadIdx.x;
  long base = ((long)b*kS)*kD + h*kHD;
  for (int i=tid;i<kS*kHD;i+=256){ int r=i/kHD, j=i%kHD;
    long g = base + (long)r*kD + j;
    Qs[i]=__half2float(Q[g]); Ks[i]=__half2float(K[g]); Vs[i]=__half2float(V[g]); }
  __syncthreads();
  const float rs = 0.28867513459481287f;
  int q0 = tid, q1 = tid+256;
  float qa[kHD], qb[kHD];
  #pragma unroll
  for(int j=0;j<kHD;j++){ qa[j]=Qs[q0*kHD+j]; qb[j]=Qs[q1*kHD+j]; }
  float acc0[kHD], acc1[kHD];
  #pragma unroll
  for(int j=0;j<kHD;j++){ acc0[j]=0.f; acc1[j]=0.f; }
  float l0=0.f, l1=0.f, m0=-1e30f, m1=-1e30f;
  for(int k=0;k<kS;k++){
    const float4* kp=(const float4*)(Ks+k*kHD);
    const float4* vp=(const float4*)(Vs+k*kHD);
    float4 ka=kp[0], kb4=kp[1], kc4=kp[2];
    float kr[kHD]={ka.x,ka.y,ka.z,ka.w,kb4.x,kb4.y,kb4.z,kb4.w,kc4.x,kc4.y,kc4.z,kc4.w};
    float s0=0.f,s1=0.f;
    #pragma unroll
    for(int j=0;j<kHD;j++){ s0+=qa[j]*kr[j]; s1+=qb[j]*kr[j]; }
    s0*=rs; s1*=rs;
    if(s0>m0){ float c=__expf(m0-s0); l0*=c;
      #pragma unroll
      for(int j=0;j<kHD;j++) acc0[j]*=c;
      m0=s0; }
    if(s1>m1){ float c=__expf(m1-s1); l1*=c;
      #pragma unroll
      for(int j=0;j<kHD;j++) acc1[j]*=c;
      m1=s1; }
    float p0=__expf(s0-m0), p1=__expf(s1-m1);
    l0+=p0; l1+=p1;
    float4 va=vp[0], vb4=vp[1], vc4=vp[2];
    float vr[kHD]={va.x,va.y,va.z,va.w,vb4.x,vb4.y,vb4.z,vb4.w,vc4.x,vc4.y,vc4.z,vc4.w};
    #pragma unroll
    for(int j=0;j<kHD;j++){ acc0[j]+=p0*vr[j]; acc1[j]+=p1*vr[j]; }
  }
  float i0=1.f/l0, i1=1.f/l1;
  #pragma unroll
  for(int j=0;j<kHD;j++){
    O[base+(long)q0*kD+j]=__float2half(acc0[j]*i0);
    O[base+(long)q1*kD+j]=__float2half(acc1[j]*i1);
  }
}

// ---------------- K4: o-proj + residual + LN (fp16 out) ----------------
__global__ void __launch_bounds__(256) k_oproj_ln(const float* __restrict__ Xres, const __half* __restrict__ O,
      const float* __restrict__ wo, const float* __restrict__ bo,
      const float* __restrict__ g, const float* __restrict__ bb,
      __half* __restrict__ Xout){
  __shared__ __align__(16) float W[kD*kD];
  __shared__ float bsh[kD], gs[kD], bs2[kD];
  __shared__ __align__(16) float res[32][kD];
  __shared__ __align__(16) float ot[32][kD];
  __shared__ float mrow[32], rstd[32];
  int tid=threadIdx.x;
  for(int i=tid;i<kD*kD;i+=256) W[i]=wo[i];
  if(tid<kD){ bsh[tid]=bo[tid]; gs[tid]=g[tid]; bs2[tid]=bb[tid]; }
  long row0=(long)blockIdx.x*32;
  for(int i=tid;i<32*kD;i+=256) ot[i/kD][i%kD]=__half2float(O[row0*kD+i]);
  __syncthreads();
  for(int i=tid;i<32*kD;i+=256){ int r=i/kD,j=i%kD;
    float acc=bsh[j];
    #pragma unroll
    for(int k=0;k<kD;k++) acc+=ot[r][k]*W[k*kD+j];
    res[r][j]=Xres[row0*kD+i]+acc;
  }
  __syncthreads();
  if(tid<32){
    float s=0.f;
    for(int j=0;j<kD;j++) s+=res[tid][j];
    float m=s*(1.f/kD); float v=0.f;
    for(int j=0;j<kD;j++){float d=res[tid][j]-m; v+=d*d;}
    mrow[tid]=m; rstd[tid]=rsqrtf(v*(1.f/kD)+1e-5f);
  }
  __syncthreads();
  for(int i=tid;i<32*kD;i+=256){int r=i/kD,j=i%kD;
    Xout[row0*kD+i]=__float2half((res[r][j]-mrow[r])*rstd[r]*gs[j]+bs2[j]); }
}

// ---------------- K5: FFN + residual + LN (fp16 in, fp32 out) ----------------
__global__ void __launch_bounds__(256) k_ffn_ln(const __half* __restrict__ Xin,
   const float* __restrict__ w1, const float* __restrict__ b1,
   const float* __restrict__ w2, const float* __restrict__ b2,
   const float* __restrict__ g, const float* __restrict__ bb,
   float* __restrict__ Xout){
  __shared__ __align__(16) float W1[kD*kFF];
  __shared__ __align__(16) float W2[kFF*kD];
  __shared__ float b1s[kFF], b2s[kD], gs[kD], bs2[kD];
  __shared__ __align__(16) float xt[16][kD];
  __shared__ __align__(16) float h1[16][kFF];
  __shared__ __align__(16) float res[16][kD];
  __shared__ float mrow[16], rstd[16];
  int tid=threadIdx.x;
  for(int i=tid;i<kD*kFF;i+=256) W1[i]=w1[i];
  for(int i=tid;i<kFF*kD;i+=256) W2[i]=w2[i];
  if(tid<kFF) b1s[tid]=b1[tid];
  if(tid<kD){ b2s[tid]=b2[tid]; gs[tid]=g[tid]; bs2[tid]=bb[tid]; }
  long row0=(long)blockIdx.x*16;
  for(int i=tid;i<16*kD;i+=256) xt[i/kD][i%kD]=__half2float(Xin[row0*kD+i]);
  __syncthreads();
  for(int i=tid;i<16*kFF;i+=256){int r=i/kFF,c=i%kFF;
    float acc=b1s[c];
    #pragma unroll
    for(int k=0;k<kD;k++) acc+=xt[r][k]*W1[k*kFF+c];
    h1[r][c]=fmaxf(acc,0.f);}
  __syncthreads();
  for(int i=tid;i<16*kD;i+=256){int r=i/kD,j=i%kD;
    float acc=b2s[j];
    #pragma unroll
    for(int k=0;k<kFF;k++) acc+=h1[r][k]*W2[k*kD+j];
    res[r][j]=xt[r][j]+acc;}
  __syncthreads();
  if(tid<16){
    float s=0.f;
    for(int j=0;j<kD;j++) s+=res[tid][j];
    float m=s*(1.f/kD); float v=0.f;
    for(int j=0;j<kD;j++){float d=res[tid][j]-m; v+=d*d;}
    mrow[tid]=m; rstd[tid]=rsqrtf(v*(1.f/kD)+1e-5f);
  }
  __syncthreads();
  for(int i=tid;i<16*kD;i+=256){int r=i/kD,j=i%kD;
    Xout[row0*kD+i]=(res[r][j]-mrow[r])*rstd[r]*gs[j]+bs2[j]; }
}

// ---------------- K6: cross K/V projection, TRANSPOSED fp16 out ----------------
// Output: KT[b][d][k] (d<48, k<512) for coalesced decoder reads.
__global__ void __launch_bounds__(256) k_ckv(const float* __restrict__ M,
    const float* __restrict__ wk, const float* __restrict__ bk,
    const float* __restrict__ wv, const float* __restrict__ bv,
    __half* __restrict__ Kc, __half* __restrict__ Vc){
  __shared__ __align__(16) float W[2][kD*kD];
  __shared__ float bias[2][kD];
  __shared__ __align__(16) float xt[32][kD];
  int tid=threadIdx.x;
  for(int i=tid;i<2*kD*kD;i+=256){int m=i/(kD*kD),e=i%(kD*kD);
    const float* w=m?wv:wk; W[m][e]=w[e];}
  for(int i=tid;i<2*kD;i+=256){int m=i/kD,e=i%kD; const float* w=m?bv:bk; bias[m][e]=w[e];}
  long row0=(long)blockIdx.x*32;
  for(int i=tid;i<32*kD;i+=256) xt[i/kD][i%kD]=M[row0*kD+i];
  __syncthreads();
  for(int i=tid;i<32*2*kD;i+=256){
    int r=i/(2*kD), c=i%(2*kD), m=c/kD, j=c%kD;
    float acc=bias[m][j];
    #pragma unroll
    for(int k=0;k<kD;k++) acc+=xt[r][k]*W[m][k*kD+j];
    long gr=row0+r; long bb2=gr>>9; long s=gr&511;
    (m?Vc:Kc)[(bb2*kD+j)*kS+s]=__float2half(acc);
  }
}

// ---------------- K0: decoder weights -> padded fp32, column-major ----------------
// Wd floats: 6 mats 48x48 col-major stride 52: swq@0 swk@2496 swv@4992 swo@7488
// cwq@9984 cwo@12480; w1 128 cols x 52 @14976; w2 48 cols x 132 @21632. Tot 27968.
__global__ void k_prep(const float* __restrict__ swq,const float* __restrict__ swk,
                       const float* __restrict__ swv,const float* __restrict__ swo,
                       const float* __restrict__ cwq,const float* __restrict__ cwo,
                       const float* __restrict__ w1,const float* __restrict__ w2,
                       float* __restrict__ Wd){
  int idx=blockIdx.x*256+threadIdx.x;
  if(idx>=26112) return;
  if(idx<13824){
    int m=idx/2304, e=idx%2304, j=e/48, k=e%48;
    const float* w = (m==0)?swq:((m==1)?swk:((m==2)?swv:((m==3)?swo:((m==4)?cwq:cwo))));
    Wd[m*2496 + j*52 + k] = w[k*48+j];
  } else if(idx<19968){
    int e=idx-13824, c=e/48, k=e%48;
    Wd[14976 + c*52 + k] = w1[k*128+c];
  } else {
    int e=idx-19968, j=e/128, u=e%128;
    Wd[21632 + j*132 + u] = w2[u*48+j];
  }
}

// ---------------- K7: decoder, one block per batch element ----------------
struct DecP {
  const float *dec_start, *sbq, *sbk, *sbv, *sbo, *ln1g, *ln1b,
              *cbq, *cbo, *ln2g, *ln2b, *fb1, *fb2, *ln3g, *ln3b, *ow, *ob;
};

__global__ void __launch_bounds__(256,1) k_dec(const __half* __restrict__ KT,
    const __half* __restrict__ VT, const float* __restrict__ Wg, DecP P,
    float* __restrict__ out){
  __shared__ __align__(16) float Wl[21632];        // 6 mats + w1 (86.5 KB); w2 stays global
  __shared__ __align__(16) float Ksl[kT*52];       // padded rows
  __shared__ __align__(16) float Vsl[kT*52];
  __shared__ __align__(16) float sc[kNH*64];
  __shared__ __align__(16) float xv[kD], qv[kD], so[kD], h1[kD], cq[kD], cov[kD], h2[kD], cur[kD];
  __shared__ __align__(16) float f1[kFF];
  __shared__ float ssum[kNH];
  int tid=threadIdx.x, b=blockIdx.x, wave=tid>>6, lane=tid&63;
  const float rs=0.28867513459481287f;

  for(int i=tid;i<21632/4;i+=256) ((float4*)Wl)[i]=((const float4*)Wg)[i];

  float c_qkvb=0, c_bo=0,c_cbq=0,c_cbo=0,c_fb2=0;
  float g1=0,bb1=0,g2=0,bb2=0,g3=0,bb3=0,c_ow=0,c_fb1=0;
  if(tid<3*kD){
    int m=tid/kD, j=tid%kD;
    c_qkvb=((m==0)?P.sbq:((m==1)?P.sbk:P.sbv))[j];
  }
  if(tid<kD){
    c_bo=P.sbo[tid]; c_cbq=P.cbq[tid]; c_cbo=P.cbo[tid]; c_fb2=P.fb2[tid];
    g1=P.ln1g[tid]; bb1=P.ln1b[tid];
    g2=P.ln2g[tid]; bb2=P.ln2b[tid];
    g3=P.ln3g[tid]; bb3=P.ln3b[tid];
    c_ow=P.ow[tid];
    cur[tid]=P.dec_start[tid];
  }
  if(tid<kFF) c_fb1=P.fb1[tid];
  float c_ob=P.ob[0];
  const __half2* KTb=(const __half2*)KT + (long)b*kD*(kS/2);
  const __half2* VTb=(const __half2*)VT + (long)b*kD*(kS/2);
  __syncthreads();

  for(int t=0;t<kT;t++){
    if(tid<kD) xv[tid]=cur[tid]+pe_val(t,tid);
    __syncthreads();
    // self q/k/v (144 threads), columns from LDS weights
    if(tid<3*kD){
      int m=tid/kD, j=tid%kD;
      const float4* x4=(const float4*)xv;
      const float4* w4=(const float4*)(Wl + m*2496 + j*52);
      float a=c_qkvb;
      #pragma unroll
      for(int k=0;k<12;k++){ float4 x=x4[k], w=w4[k];
        a+=x.x*w.x+x.y*w.y+x.z*w.z+x.w*w.w; }
      if(m==0) qv[j]=a; else if(m==1) Ksl[t*52+j]=a; else Vsl[t*52+j]=a;
    }
    __syncthreads();
    // self-attn: wave=head, lane=key
    {
      float s=-1e30f;
      if(lane<=t){
        const float4* kp=(const float4*)(Ksl + lane*52 + wave*kHD);
        const float4* qp=(const float4*)(qv + wave*kHD);
        float a=0.f;
        #pragma unroll
        for(int u=0;u<3;u++){ float4 qq=qp[u], kk=kp[u];
          a+=qq.x*kk.x+qq.y*kk.y+qq.z*kk.z+qq.w*kk.w; }
        s=a*rs;
      }
      float m=wmax(s);
      float p=(lane<=t)?__expf(s-m):0.f;
      float l=wsum(p);
      sc[wave*64+lane]=p;
      if(lane==0) ssum[wave]=l;
    }
    __syncthreads();
    if(tid<kD){
      int h=tid/kHD;
      float acc=0.f;
      for(int k=0;k<=t;k++) acc+=sc[h*64+k]*Vsl[k*52+tid];
      so[tid]=acc/ssum[h];
    }
    __syncthreads();
    // self o-proj + residual (rr in-register into LN1)
    float rr=0.f;
    if(tid<kD){
      const float4* s4=(const float4*)so;
      const float4* w4=(const float4*)(Wl+7488+tid*52);
      float a=c_bo;
      #pragma unroll
      for(int k=0;k<12;k++){ float4 x=s4[k], w=w4[k];
        a+=x.x*w.x+x.y*w.y+x.z*w.z+x.w*w.w; }
      rr=xv[tid]+a;
    }
    if(tid<64){
      float mean=wsum(rr)*(1.f/48.f);
      float d=(tid<kD)?(rr-mean):0.f;
      float rstd=rsqrtf(wsum(d*d)*(1.f/48.f)+1e-5f);
      if(tid<kD) h1[tid]=(rr-mean)*rstd*g1+bb1;
    }
    __syncthreads();
    // cross-q
    if(tid<kD){
      const float4* x4=(const float4*)h1;
      const float4* w4=(const float4*)(Wl+9984+tid*52);
      float a=c_cbq;
      #pragma unroll
      for(int k=0;k<12;k++){ float4 x=x4[k], w=w4[k];
        a+=x.x*w.x+x.y*w.y+x.z*w.z+x.w*w.w; }
      cq[tid]=a;
    }
    __syncthreads();
    // cross-attn over 512 keys: head = wave, coalesced half2 (L2-hot)
    {
      float qh[kHD];
      #pragma unroll
      for(int u=0;u<kHD;u++) qh[u]=cq[wave*kHD+u];
      const __half2* Kb=KTb+(wave*kHD)*(kS/2);
      const __half2* Vb=VTb+(wave*kHD)*(kS/2);
      float sx[8];
      #pragma unroll
      for(int i=0;i<4;i++){
        int pp=lane+64*i;
        float ax=0.f, ay=0.f;
        #pragma unroll
        for(int u=0;u<kHD;u++){ float2 kv=__half22float2(Kb[u*(kS/2)+pp]);
          ax+=qh[u]*kv.x; ay+=qh[u]*kv.y; }
        sx[2*i]=ax*rs; sx[2*i+1]=ay*rs;
      }
      float mx=sx[0];
      #pragma unroll
      for(int i=1;i<8;i++) mx=fmaxf(mx,sx[i]);
      mx=wmax(mx);
      float p[8], l=0.f;
      #pragma unroll
      for(int i=0;i<8;i++){ p[i]=__expf(sx[i]-mx); l+=p[i]; }
      l=wsum(l);
      float inv=1.f/l;
      float acc[kHD];
      #pragma unroll
      for(int u=0;u<kHD;u++) acc[u]=0.f;
      #pragma unroll
      for(int i=0;i<4;i++){
        int pp=lane+64*i;
        #pragma unroll
        for(int u=0;u<kHD;u++){ float2 vv=__half22float2(Vb[u*(kS/2)+pp]);
          acc[u]+=p[2*i]*vv.x+p[2*i+1]*vv.y; }
      }
      #pragma unroll
      for(int u=0;u<kHD;u++) acc[u]=wsum(acc[u]);
      if(lane==0){
        #pragma unroll
        for(int u=0;u<kHD;u++) cov[wave*kHD+u]=acc[u]*inv;
      }
    }
    __syncthreads();
    // cross o-proj + residual (rr in-register into LN2)
    rr=0.f;
    if(tid<kD){
      const float4* x4=(const float4*)cov;
      const float4* w4=(const float4*)(Wl+12480+tid*52);
      float a=c_cbo;
      #pragma unroll
      for(int k=0;k<12;k++){ float4 x=x4[k], w=w4[k];
        a+=x.x*w.x+x.y*w.y+x.z*w.z+x.w*w.w; }
      rr=h1[tid]+a;
    }
    if(tid<64){
      float mean=wsum(rr)*(1.f/48.f);
      float d=(tid<kD)?(rr-mean):0.f;
      float rstd=rsqrtf(wsum(d*d)*(1.f/48.f)+1e-5f);
      if(tid<kD) h2[tid]=(rr-mean)*rstd*g2+bb2;
    }
    __syncthreads();
    // FFN layer 1 (128 threads), w1 from LDS
    if(tid<kFF){
      const float4* x4=(const float4*)h2;
      const float4* w4=(const float4*)(Wl+14976+tid*52);
      float a=c_fb1;
      #pragma unroll
      for(int k=0;k<12;k++){ float4 x=x4[k], w=w4[k];
        a+=x.x*w.x+x.y*w.y+x.z*w.z+x.w*w.w; }
      f1[tid]=fmaxf(a,0.f);
    }
    __syncthreads();
    // FFN layer 2 + residual; w2 column from GLOBAL (L2-hot, 12-deep pipeline)
    rr=0.f;
    if(tid<kD){
      const float4* x4=(const float4*)f1;
      const float4* w4=(const float4*)(Wg+21632+tid*132);
      float a=c_fb2;
      #pragma unroll
      for(int k=0;k<32;k++){ float4 x=x4[k], w=w4[k];
        a+=x.x*w.x+x.y*w.y+x.z*w.z+x.w*w.w; }
      rr=h2[tid]+a;
    }
    if(tid<64){
      float mean=wsum(rr)*(1.f/48.f);
      float d=(tid<kD)?(rr-mean):0.f;
      float rstd=rsqrtf(wsum(d*d)*(1.f/48.f)+1e-5f);
      float cv=0.f;
      if(tid<kD){ cv=(rr-mean)*rstd*g3+bb3; cur[tid]=cv; }
      float y=wsum(cv*c_ow);
      if(tid==0) out[b*kT+t]=y+c_ob;
    }
    __syncthreads();
  }
}

extern "C" void kernel_launch(void* const* d_in, const int* in_sizes, int n_in,
                              void* d_out, int out_size, void* d_ws, size_t ws_size,
                              hipStream_t stream){
  // ws (~30 MiB): Wd fp32 27968 (reserve 32768 floats), A fp32 NB, H1/H2/H3 fp16 NB.
  float* ws = (float*)d_ws;
  float* Wd = ws;
  const size_t NB = (size_t)kB*kS*kD;     // 3,145,728
  float*  A  = ws + 32768;
  __half* H1 = (__half*)(A + NB);
  __half* H2 = H1 + NB;
  __half* H3 = H2 + NB;

  k_embed<<<(kB*kS*kD+255)/256,256,0,stream>>>((const float*)d_in[0],(const float*)d_in[1],(const float*)d_in[2],A);
  k_qkv  <<<(kB*kS)/32,256,0,stream>>>(A,(const float*)d_in[4],(const float*)d_in[5],(const float*)d_in[6],
                                       (const float*)d_in[7],(const float*)d_in[8],(const float*)d_in[9],H1,H2,H3);
  k_attn <<<kB*kNH,256,0,stream>>>(H1,H2,H3,H1);
  k_oproj_ln<<<(kB*kS)/32,256,0,stream>>>(A,H1,(const float*)d_in[10],(const float*)d_in[11],
                                          (const float*)d_in[12],(const float*)d_in[13],H2);
  k_ffn_ln  <<<(kB*kS)/16,256,0,stream>>>(H2,(const float*)d_in[14],(const float*)d_in[15],(const float*)d_in[16],
                                          (const float*)d_in[17],(const float*)d_in[18],(const float*)d_in[19],A);
  k_ckv     <<<(kB*kS)/32,256,0,stream>>>(A,(const float*)d_in[32],(const float*)d_in[33],
                                          (const float*)d_in[34],(const float*)d_in[35],H1,H3);
  k_prep    <<<(26112+255)/256,256,0,stream>>>((const float*)d_in[20],(const float*)d_in[22],(const float*)d_in[24],
                                               (const float*)d_in[26],(const float*)d_in[30],(const float*)d_in[36],
                                               (const float*)d_in[40],(const float*)d_in[42],Wd);
  DecP P;
  P.dec_start=(const float*)d_in[3];
  P.sbq=(const float*)d_in[21]; P.sbk=(const float*)d_in[23]; P.sbv=(const float*)d_in[25]; P.sbo=(const float*)d_in[27];
  P.ln1g=(const float*)d_in[28]; P.ln1b=(const float*)d_in[29];
  P.cbq=(const float*)d_in[31]; P.cbo=(const float*)d_in[37];
  P.ln2g=(const float*)d_in[38]; P.ln2b=(const float*)d_in[39];
  P.fb1=(const float*)d_in[41]; P.fb2=(const float*)d_in[43];
  P.ln3g=(const float*)d_in[44]; P.ln3b=(const float*)d_in[45];
  P.ow=(const float*)d_in[46]; P.ob=(const float*)d_in[47];
  k_dec<<<kB,256,0,stream>>>(H1,H3,Wd,P,(float*)d_out);
}

// Round 7
// 1037.149 us; speedup vs baseline: 1.2835x; 1.0856x over previous
//
#include <hip/hip_runtime.h>
#include <hip/hip_bf16.h>
#include <hip/hip_fp16.h>

// Inputs/outputs are FP32 (verified R3/R6).

constexpr int kB  = 128;
constexpr int kS  = 512;
constexpr int kT  = 64;
constexpr int kD  = 48;
constexpr int kFF = 128;
constexpr int kNH = 4;
constexpr int kHD = 12;

// wave-synchronous fence: stops compiler reordering/caching LDS ops across it.
// HW: DS ops from one wave are processed in order -> same-wave LDS RAW is safe.
__device__ __forceinline__ void wsync(){
  __builtin_amdgcn_wave_barrier();
  asm volatile("" ::: "memory");
}

__device__ __forceinline__ float wsum(float v){
  #pragma unroll
  for(int o=32;o>=1;o>>=1) v += __shfl_xor(v,o,64);
  return v;
}

// pe[p, 2i] = sin(p * exp(-2i*ln(10000)/48)), pe[p, 2i+1] = cos(...)
__device__ __forceinline__ float pe_val(int p, int j){
  int i = j >> 1;
  float f = expf(-0.19188209108283716f * (float)(2*i));
  float a = (float)p * f;
  return (j & 1) ? cosf(a) : sinf(a);
}

__device__ __forceinline__ float dot12(const float4* x, const float4* w){
  float a=0.f;
  #pragma unroll
  for(int k=0;k<12;k++){ float4 xx=x[k], ww=w[k];
    a+=xx.x*ww.x+xx.y*ww.y+xx.z*ww.z+xx.w*ww.w; }
  return a;
}
__device__ __forceinline__ float dot32(const float4* x, const float4* w){
  float a=0.f;
  #pragma unroll
  for(int k=0;k<32;k++){ float4 xx=x[k], ww=w[k];
    a+=xx.x*ww.x+xx.y*ww.y+xx.z*ww.z+xx.w*ww.w; }
  return a;
}

// ---------------- K1: embed + PE -> X0 (fp32) ----------------
__global__ void k_embed(const float* __restrict__ src, const float* __restrict__ in_w,
                        const float* __restrict__ in_b, float* __restrict__ X0){
  int idx = blockIdx.x*256 + threadIdx.x;
  if (idx >= kB*kS*kD) return;
  int j = idx % kD; int bs = idx / kD; int s = bs % kS;
  float v = (src[bs] * in_w[j] + in_b[j]) * 6.928203230275509f;
  X0[idx] = v + pe_val(s, j);
}

// ---------------- K2: encoder QKV projection (fp16 out), W transposed in LDS ----------------
__global__ void __launch_bounds__(256) k_qkv(const float* __restrict__ X,
    const float* __restrict__ wq, const float* __restrict__ bq,
    const float* __restrict__ wk, const float* __restrict__ bk,
    const float* __restrict__ wv, const float* __restrict__ bv,
    __half* __restrict__ Q, __half* __restrict__ K, __half* __restrict__ V){
  __shared__ __align__(16) float W[3*2496];     // W^T: [m][col j][k], col stride 52
  __shared__ __align__(16) float bias[3*kD];
  __shared__ __align__(16) float xt[32*kD];
  int tid = threadIdx.x;
  for (int i=tid;i<3*2304;i+=256){ int m=i/2304, e=i%2304, k=e/48, j=e%48;
    const float* w = (m==0)?wq:((m==1)?wk:wv);
    W[m*2496 + j*52 + k] = w[e]; }
  for (int i=tid;i<3*kD;i+=256){ int m=i/kD,e=i%kD;
    const float* w=(m==0)?bq:((m==1)?bk:bv); bias[i]=w[e]; }
  long row0 = (long)blockIdx.x*32;
  for (int i=tid;i<32*kD;i+=256) xt[i] = X[row0*kD + i];
  __syncthreads();
  int r = tid>>3, c0 = tid&7;
  float4 xr[12];
  const float4* xp=(const float4*)(xt + r*kD);
  #pragma unroll
  for(int u=0;u<12;u++) xr[u]=xp[u];
  for (int c=c0; c<3*kD; c+=8){
    int m=c/kD, j=c%kD;
    float acc = bias[m*kD+j] + dot12(xr, (const float4*)(W + m*2496 + j*52));
    __half* o = (m==0)?Q:((m==1)?K:V);
    o[(row0+r)*kD+j]=__float2half(acc);
  }
}

// ---------------- K3: encoder attention (unchanged, passing) ----------------
__global__ void __launch_bounds__(256) k_attn(const __half* Q, const __half* __restrict__ K,
                       const __half* __restrict__ V, __half* O){
  int b = blockIdx.x / kNH, h = blockIdx.x % kNH;
  __shared__ __align__(16) float Qs[kS*kHD];
  __shared__ __align__(16) float Ks[kS*kHD];
  __shared__ __align__(16) float Vs[kS*kHD];
  int tid = threadIdx.x;
  long base = ((long)b*kS)*kD + h*kHD;
  for (int i=tid;i<kS*kHD;i+=256){ int r=i/kHD, j=i%kHD;
    long g = base + (long)r*kD + j;
    Qs[i]=__half2float(Q[g]); Ks[i]=__half2float(K[g]); Vs[i]=__half2float(V[g]); }
  __syncthreads();
  const float rs = 0.28867513459481287f;
  int q0 = tid, q1 = tid+256;
  float qa[kHD], qb[kHD];
  #pragma unroll
  for(int j=0;j<kHD;j++){ qa[j]=Qs[q0*kHD+j]*rs; qb[j]=Qs[q1*kHD+j]*rs; }
  float acc0[kHD], acc1[kHD];
  #pragma unroll
  for(int j=0;j<kHD;j++){ acc0[j]=0.f; acc1[j]=0.f; }
  float l0=0.f, l1=0.f;
  for(int k=0;k<kS;k++){
    const float4* kp=(const float4*)(Ks+k*kHD);
    const float4* vp=(const float4*)(Vs+k*kHD);
    float4 ka=kp[0], kb4=kp[1], kc4=kp[2];
    float kr[kHD]={ka.x,ka.y,ka.z,ka.w,kb4.x,kb4.y,kb4.z,kb4.w,kc4.x,kc4.y,kc4.z,kc4.w};
    float s0=0.f,s1=0.f;
    #pragma unroll
    for(int j=0;j<kHD;j++){ s0+=qa[j]*kr[j]; s1+=qb[j]*kr[j]; }
    float p0=__expf(s0), p1=__expf(s1);   // |s|<~42 << 88: exp-safe
    l0+=p0; l1+=p1;
    float4 va=vp[0], vb4=vp[1], vc4=vp[2];
    float vr[kHD]={va.x,va.y,va.z,va.w,vb4.x,vb4.y,vb4.z,vb4.w,vc4.x,vc4.y,vc4.z,vc4.w};
    #pragma unroll
    for(int j=0;j<kHD;j++){ acc0[j]+=p0*vr[j]; acc1[j]+=p1*vr[j]; }
  }
  float i0=1.f/l0, i1=1.f/l1;
  #pragma unroll
  for(int j=0;j<kHD;j++){
    O[base+(long)q0*kD+j]=__float2half(acc0[j]*i0);
    O[base+(long)q1*kD+j]=__float2half(acc1[j]*i1);
  }
}

// ---------------- K4: o-proj + residual + LN (fp16 out), W^T in LDS ----------------
__global__ void __launch_bounds__(256) k_oproj_ln(const float* __restrict__ Xres, const __half* __restrict__ O,
      const float* __restrict__ wo, const float* __restrict__ bo,
      const float* __restrict__ g, const float* __restrict__ bb,
      __half* __restrict__ Xout){
  __shared__ __align__(16) float W[kD*52];
  __shared__ float bsh[kD], gs[kD], bs2[kD];
  __shared__ __align__(16) float res[32*kD];
  __shared__ __align__(16) float ot[32*kD];
  __shared__ float mrow[32], rstd[32];
  int tid=threadIdx.x;
  for(int i=tid;i<kD*kD;i+=256){ int k=i/48, j=i%48; W[j*52+k]=wo[i]; }
  if(tid<kD){ bsh[tid]=bo[tid]; gs[tid]=g[tid]; bs2[tid]=bb[tid]; }
  long row0=(long)blockIdx.x*32;
  for(int i=tid;i<32*kD;i+=256) ot[i]=__half2float(O[row0*kD+i]);
  __syncthreads();
  int r=tid>>3, c0=tid&7;
  float4 orow[12];
  const float4* op=(const float4*)(ot + r*kD);
  #pragma unroll
  for(int u=0;u<12;u++) orow[u]=op[u];
  for(int j=c0;j<kD;j+=8){
    float acc=bsh[j]+dot12(orow,(const float4*)(W+j*52));
    res[r*kD+j]=Xres[row0*kD + r*kD + j]+acc;
  }
  __syncthreads();
  if(tid<32){
    float s=0.f, s2=0.f;
    for(int j=0;j<kD;j++){ float v=res[tid*kD+j]; s+=v; s2+=v*v; }
    float m=s*(1.f/kD);
    mrow[tid]=m; rstd[tid]=rsqrtf(s2*(1.f/kD)-m*m+1e-5f);
  }
  __syncthreads();
  for(int i=tid;i<32*kD;i+=256){int r2=i/kD,j=i%kD;
    Xout[row0*kD+i]=__float2half((res[i]-mrow[r2])*rstd[r2]*gs[j]+bs2[j]); }
}

// ---------------- K5: FFN + residual + LN (fp16 in, fp32 out), W^T in LDS ----------------
__global__ void __launch_bounds__(256) k_ffn_ln(const __half* __restrict__ Xin,
   const float* __restrict__ w1, const float* __restrict__ b1,
   const float* __restrict__ w2, const float* __restrict__ b2,
   const float* __restrict__ g, const float* __restrict__ bb,
   float* __restrict__ Xout){
  __shared__ __align__(16) float W1[kFF*52];    // W1^T: col c (of 128) stride 52
  __shared__ __align__(16) float W2[kD*132];    // W2^T: col j (of 48) stride 132
  __shared__ float b1s[kFF], b2s[kD], gs[kD], bs2[kD];
  __shared__ __align__(16) float xt[16*kD];
  __shared__ __align__(16) float h1v[16*kFF];
  __shared__ __align__(16) float res[16*kD];
  __shared__ float mrow[16], rstd[16];
  int tid=threadIdx.x;
  for(int i=tid;i<kD*kFF;i+=256){ int k=i/128, c=i%128; W1[c*52+k]=w1[i]; }
  for(int i=tid;i<kFF*kD;i+=256){ int u=i/48, j=i%48; W2[j*132+u]=w2[i]; }
  if(tid<kFF) b1s[tid]=b1[tid];
  if(tid<kD){ b2s[tid]=b2[tid]; gs[tid]=g[tid]; bs2[tid]=bb[tid]; }
  long row0=(long)blockIdx.x*16;
  for(int i=tid;i<16*kD;i+=256) xt[i]=__half2float(Xin[row0*kD+i]);
  __syncthreads();
  int r=tid>>4, c0=tid&15;
  {
    float4 xr[12];
    const float4* xp=(const float4*)(xt + r*kD);
    #pragma unroll
    for(int u=0;u<12;u++) xr[u]=xp[u];
    for(int c=c0;c<kFF;c+=16){
      float acc=b1s[c]+dot12(xr,(const float4*)(W1+c*52));
      h1v[r*kFF+c]=fmaxf(acc,0.f);
    }
  }
  __syncthreads();
  {
    float4 hr[32];
    const float4* hp=(const float4*)(h1v + r*kFF);
    #pragma unroll
    for(int u=0;u<32;u++) hr[u]=hp[u];
    for(int j=c0;j<kD;j+=16){
      float acc=b2s[j]+dot32(hr,(const float4*)(W2+j*132));
      res[r*kD+j]=xt[r*kD+j]+acc;
    }
  }
  __syncthreads();
  if(tid<16){
    float s=0.f, s2=0.f;
    for(int j=0;j<kD;j++){ float v=res[tid*kD+j]; s+=v; s2+=v*v; }
    float m=s*(1.f/kD);
    mrow[tid]=m; rstd[tid]=rsqrtf(s2*(1.f/kD)-m*m+1e-5f);
  }
  __syncthreads();
  for(int i=tid;i<16*kD;i+=256){int r2=i/kD,j=i%kD;
    Xout[row0*kD+i]=(res[i]-mrow[r2])*rstd[r2]*gs[j]+bs2[j]; }
}

// ---------------- K6: cross K/V projection, TRANSPOSED fp16 out, W^T in LDS ----------------
__global__ void __launch_bounds__(256) k_ckv(const float* __restrict__ M,
    const float* __restrict__ wk, const float* __restrict__ bk,
    const float* __restrict__ wv, const float* __restrict__ bv,
    __half* __restrict__ Kc, __half* __restrict__ Vc){
  __shared__ __align__(16) float W[2*2496];
  __shared__ float bias[2*kD];
  __shared__ __align__(16) float xt[32*kD];
  int tid=threadIdx.x;
  for(int i=tid;i<2*2304;i+=256){ int m=i/2304, e=i%2304, k=e/48, j=e%48;
    W[m*2496 + j*52 + k] = (m?wv:wk)[e]; }
  for(int i=tid;i<2*kD;i+=256){ int m=i/kD,e=i%kD; bias[i]=(m?bv:bk)[e]; }
  long row0=(long)blockIdx.x*32;
  for(int i=tid;i<32*kD;i+=256) xt[i]=M[row0*kD+i];
  __syncthreads();
  int r=tid>>3, c0=tid&7;
  float4 xr[12];
  const float4* xp=(const float4*)(xt + r*kD);
  #pragma unroll
  for(int u=0;u<12;u++) xr[u]=xp[u];
  long gr=row0+r; long bb2=gr>>9; long s=gr&511;
  for(int c=c0;c<2*kD;c+=8){
    int m=c/kD, j=c%kD;
    float acc=bias[m*kD+j]+dot12(xr,(const float4*)(W+m*2496+j*52));
    (m?Vc:Kc)[(bb2*kD+j)*kS+s]=__float2half(acc);
  }
}

// ---------------- K0: decoder weights -> padded fp32, column-major (unchanged) ----------------
__global__ void k_prep(const float* __restrict__ swq,const float* __restrict__ swk,
                       const float* __restrict__ swv,const float* __restrict__ swo,
                       const float* __restrict__ cwq,const float* __restrict__ cwo,
                       const float* __restrict__ w1,const float* __restrict__ w2,
                       float* __restrict__ Wd){
  int idx=blockIdx.x*256+threadIdx.x;
  if(idx>=26112) return;
  if(idx<13824){
    int m=idx/2304, e=idx%2304, j=e/48, k=e%48;
    const float* w = (m==0)?swq:((m==1)?swk:((m==2)?swv:((m==3)?swo:((m==4)?cwq:cwo))));
    Wd[m*2496 + j*52 + k] = w[k*48+j];
  } else if(idx<19968){
    int e=idx-13824, c=e/48, k=e%48;
    Wd[14976 + c*52 + k] = w1[k*128+c];
  } else {
    int e=idx-19968, j=e/128, u=e%128;
    Wd[21632 + j*132 + u] = w2[u*48+j];
  }
}

// ---------------- K7: decoder — wave-0-synchronous serial chain, 2 barriers/step ----------------
struct DecP {
  const float *dec_start, *sbq, *sbk, *sbv, *sbo, *ln1g, *ln1b,
              *cbq, *cbo, *ln2g, *ln2b, *fb1, *fb2, *ln3g, *ln3b, *ow, *ob;
};

__global__ void __launch_bounds__(256,1) k_dec(const __half* __restrict__ KT,
    const __half* __restrict__ VT, const float* __restrict__ Wg, DecP P,
    float* __restrict__ out){
  __shared__ __align__(16) float Wl[27968];        // all decoder weights incl. w2 (109.25 KB)
  __shared__ __align__(16) float peL[kT*kD];       // 12 KB
  __shared__ __align__(16) float Ksl[kT*52];
  __shared__ __align__(16) float Vsl[kT*52];
  __shared__ __align__(16) float sc[kNH*64];
  __shared__ __align__(16) float xvS[kD], qvS[kD], soS[kD], h1S[kD], h2S[kD], cqS[kD], covS[kD];
  __shared__ __align__(16) float f1S[kFF];
  int tid=threadIdx.x, b=blockIdx.x, wave=tid>>6, lane=tid&63;
  const float rs=0.28867513459481287f;

  for(int i=tid;i<27968/4;i+=256) ((float4*)Wl)[i]=((const float4*)Wg)[i];
  for(int i=tid;i<kT*kD;i+=256) peL[i]=pe_val(i/kD,i%kD);

  float cur=0, c_bq=0,c_bk=0,c_bv=0,c_bo=0,c_cbq=0,c_cbo=0,c_fb2=0;
  float g1=0,bb1=0,g2=0,bb2=0,g3=0,bb3=0,c_ow=0,fb1a=0,fb1b=0;
  if(wave==0){
    if(lane<kD){
      cur=P.dec_start[lane];
      c_bq=P.sbq[lane]; c_bk=P.sbk[lane]; c_bv=P.sbv[lane];
      c_bo=P.sbo[lane]; c_cbq=P.cbq[lane]; c_cbo=P.cbo[lane];
      c_fb2=P.fb2[lane];
      g1=P.ln1g[lane]; bb1=P.ln1b[lane];
      g2=P.ln2g[lane]; bb2=P.ln2b[lane];
      g3=P.ln3g[lane]; bb3=P.ln3b[lane];
      c_ow=P.ow[lane];
    }
    fb1a=P.fb1[lane]; fb1b=P.fb1[lane+64];
  }
  float c_ob=P.ob[0];
  const __half2* KTb=(const __half2*)KT + (long)b*kD*(kS/2);
  const __half2* VTb=(const __half2*)VT + (long)b*kD*(kS/2);
  __syncthreads();

  float h1=0, h2=0;
  for(int t=0;t<kT;t++){
    // ===== wave-0 serial section A (wave-sync only) =====
    if(wave==0){
      float xv=0;
      if(lane<kD){ xv=cur+peL[t*kD+lane]; xvS[lane]=xv; }
      wsync();
      if(lane<kD){                      // self q/k/v, col = lane
        const float4* x4=(const float4*)xvS;
        float aq=c_bq+dot12(x4,(const float4*)(Wl+       lane*52));
        float ak=c_bk+dot12(x4,(const float4*)(Wl+2496 + lane*52));
        float av=c_bv+dot12(x4,(const float4*)(Wl+4992 + lane*52));
        qvS[lane]=aq; Ksl[t*52+lane]=ak; Vsl[t*52+lane]=av;
      }
      wsync();
      {                                  // self-attn: lane = key, no-max softmax
        float p0=0,p1=0,p2=0,p3=0;
        if(lane<=t){
          const float4* kr=(const float4*)(Ksl+lane*52);
          const float4* q4=(const float4*)qvS;
          float a0=0,a1=0,a2=0,a3=0;
          #pragma unroll
          for(int u=0;u<3;u++){
            float4 k0=kr[u], k1=kr[3+u], k2=kr[6+u], k3=kr[9+u];
            float4 q0=q4[u], q1=q4[3+u], q2=q4[6+u], q3=q4[9+u];
            a0+=q0.x*k0.x+q0.y*k0.y+q0.z*k0.z+q0.w*k0.w;
            a1+=q1.x*k1.x+q1.y*k1.y+q1.z*k1.z+q1.w*k1.w;
            a2+=q2.x*k2.x+q2.y*k2.y+q2.z*k2.z+q2.w*k2.w;
            a3+=q3.x*k3.x+q3.y*k3.y+q3.z*k3.z+q3.w*k3.w;
          }
          p0=__expf(a0*rs); p1=__expf(a1*rs); p2=__expf(a2*rs); p3=__expf(a3*rs);
        }
        float l0=wsum(p0), l1=wsum(p1), l2=wsum(p2), l3=wsum(p3);
        sc[lane]    =p0*(1.f/l0);
        sc[64+lane] =p1*(1.f/l1);
        sc[128+lane]=p2*(1.f/l2);
        sc[192+lane]=p3*(1.f/l3);
      }
      wsync();
      if(lane<kD){                       // P·V
        const float* scp=sc+(lane/kHD)*64;
        float so=0.f;
        for(int k=0;k<=t;k++) so+=scp[k]*Vsl[k*52+lane];
        soS[lane]=so;
      }
      wsync();
      float rr=0;
      if(lane<kD)                        // self o-proj + residual
        rr=xv+c_bo+dot12((const float4*)soS,(const float4*)(Wl+7488+lane*52));
      float s1=wsum(rr), s2=wsum(rr*rr); // LN1: independent butterflies
      float mean=s1*(1.f/48.f);
      float rstd=rsqrtf(s2*(1.f/48.f)-mean*mean+1e-5f);
      h1=0;
      if(lane<kD){ h1=(rr-mean)*rstd*g1+bb1; h1S[lane]=h1; }
      wsync();
      if(lane<kD)                        // cross-q
        cqS[lane]=c_cbq+dot12((const float4*)h1S,(const float4*)(Wl+9984+lane*52));
    }
    __syncthreads();   // barrier 1: cq -> all waves
    // ===== all waves: cross-attn over 512 keys, head = wave =====
    {
      float qh[kHD];
      #pragma unroll
      for(int u=0;u<kHD;u++) qh[u]=cqS[wave*kHD+u]*rs;
      const __half2* Kb=KTb+(wave*kHD)*(kS/2);
      const __half2* Vb=VTb+(wave*kHD)*(kS/2);
      float p[8]; float l=0.f;
      #pragma unroll
      for(int i=0;i<4;i++){
        int pp=lane+64*i;
        float ax=0.f, ay=0.f;
        #pragma unroll
        for(int u=0;u<kHD;u++){ float2 kv=__half22float2(Kb[u*(kS/2)+pp]);
          ax+=qh[u]*kv.x; ay+=qh[u]*kv.y; }
        p[2*i]=__expf(ax); p[2*i+1]=__expf(ay);   // no-max: |s|<~30
        l+=p[2*i]+p[2*i+1];
      }
      l=wsum(l);
      float inv=1.f/l;
      float acc[kHD];
      #pragma unroll
      for(int u=0;u<kHD;u++) acc[u]=0.f;
      #pragma unroll
      for(int i=0;i<4;i++){
        int pp=lane+64*i;
        #pragma unroll
        for(int u=0;u<kHD;u++){ float2 vv=__half22float2(Vb[u*(kS/2)+pp]);
          acc[u]+=p[2*i]*vv.x+p[2*i+1]*vv.y; }
      }
      #pragma unroll
      for(int u=0;u<kHD;u++) acc[u]=wsum(acc[u]);
      if(lane==0){
        #pragma unroll
        for(int u=0;u<kHD;u++) covS[wave*kHD+u]=acc[u]*inv;
      }
    }
    __syncthreads();   // barrier 2: cov -> wave 0
    // ===== wave-0 serial section B =====
    if(wave==0){
      float rr=0;
      if(lane<kD)                        // cross o-proj + residual (h1 in-register)
        rr=h1+c_cbo+dot12((const float4*)covS,(const float4*)(Wl+12480+lane*52));
      float s1=wsum(rr), s2=wsum(rr*rr); // LN2
      float mean=s1*(1.f/48.f);
      float rstd=rsqrtf(s2*(1.f/48.f)-mean*mean+1e-5f);
      h2=0;
      if(lane<kD){ h2=(rr-mean)*rstd*g2+bb2; h2S[lane]=h2; }
      wsync();
      {                                  // FFN1: 2 cols/lane
        const float4* x4=(const float4*)h2S;
        float a=fb1a+dot12(x4,(const float4*)(Wl+14976+lane*52));
        float c=fb1b+dot12(x4,(const float4*)(Wl+14976+(lane+64)*52));
        f1S[lane]=fmaxf(a,0.f); f1S[lane+64]=fmaxf(c,0.f);
      }
      wsync();
      rr=0;
      if(lane<kD)                        // FFN2 + residual (h2 in-register)
        rr=h2+c_fb2+dot32((const float4*)f1S,(const float4*)(Wl+21632+lane*132));
      s1=wsum(rr); s2=wsum(rr*rr);       // LN3
      mean=s1*(1.f/48.f);
      rstd=rsqrtf(s2*(1.f/48.f)-mean*mean+1e-5f);
      cur=0;
      if(lane<kD) cur=(rr-mean)*rstd*g3+bb3;
      float y=wsum(cur*c_ow);
      if(lane==0) out[b*kT+t]=y+c_ob;
    }
  }
}

extern "C" void kernel_launch(void* const* d_in, const int* in_sizes, int n_in,
                              void* d_out, int out_size, void* d_ws, size_t ws_size,
                              hipStream_t stream){
  // ws (~30 MiB): Wd fp32 27968 (reserve 32768 floats), A fp32 NB, H1/H2/H3 fp16 NB.
  float* ws = (float*)d_ws;
  float* Wd = ws;
  const size_t NB = (size_t)kB*kS*kD;     // 3,145,728
  float*  A  = ws + 32768;
  __half* H1 = (__half*)(A + NB);
  __half* H2 = H1 + NB;
  __half* H3 = H2 + NB;

  k_embed<<<(kB*kS*kD+255)/256,256,0,stream>>>((const float*)d_in[0],(const float*)d_in[1],(const float*)d_in[2],A);
  k_qkv  <<<(kB*kS)/32,256,0,stream>>>(A,(const float*)d_in[4],(const float*)d_in[5],(const float*)d_in[6],
                                       (const float*)d_in[7],(const float*)d_in[8],(const float*)d_in[9],H1,H2,H3);
  k_attn <<<kB*kNH,256,0,stream>>>(H1,H2,H3,H1);
  k_oproj_ln<<<(kB*kS)/32,256,0,stream>>>(A,H1,(const float*)d_in[10],(const float*)d_in[11],
                                          (const float*)d_in[12],(const float*)d_in[13],H2);
  k_ffn_ln  <<<(kB*kS)/16,256,0,stream>>>(H2,(const float*)d_in[14],(const float*)d_in[15],(const float*)d_in[16],
                                          (const float*)d_in[17],(const float*)d_in[18],(const float*)d_in[19],A);
  k_ckv     <<<(kB*kS)/32,256,0,stream>>>(A,(const float*)d_in[32],(const float*)d_in[33],
                                          (const float*)d_in[34],(const float*)d_in[35],H1,H3);
  k_prep    <<<(26112+255)/256,256,0,stream>>>((const float*)d_in[20],(const float*)d_in[22],(const float*)d_in[24],
                                               (const float*)d_in[26],(const float*)d_in[30],(const float*)d_in[36],
                                               (const float*)d_in[40],(const float*)d_in[42],Wd);
  DecP P;
  P.dec_start=(const float*)d_in[3];
  P.sbq=(const float*)d_in[21]; P.sbk=(const float*)d_in[23]; P.sbv=(const float*)d_in[25]; P.sbo=(const float*)d_in[27];
  P.ln1g=(const float*)d_in[28]; P.ln1b=(const float*)d_in[29];
  P.cbq=(const float*)d_in[31]; P.cbo=(const float*)d_in[37];
  P.ln2g=(const float*)d_in[38]; P.ln2b=(const float*)d_in[39];
  P.fb1=(const float*)d_in[41]; P.fb2=(const float*)d_in[43];
  P.ln3g=(const float*)d_in[44]; P.ln3b=(const float*)d_in[45];
  P.ow=(const float*)d_in[46]; P.ob=(const float*)d_in[47];
  k_dec<<<kB,256,0,stream>>>(H1,H3,Wd,P,(float*)d_out);
}

// Round 8
// 984.886 us; speedup vs baseline: 1.3517x; 1.0531x over previous
//
#include <hip/hip_runtime.h>
#include <hip/hip_bf16.h>
#include <hip/hip_fp16.h>

// Inputs/outputs are FP32 (verified R3/R6).

constexpr int kB  = 128;
constexpr int kS  = 512;
constexpr int kT  = 64;
constexpr int kD  = 48;
constexpr int kFF = 128;
constexpr int kNH = 4;
constexpr int kHD = 12;

__device__ __forceinline__ void wsync(){
  __builtin_amdgcn_wave_barrier();
  asm volatile("" ::: "memory");
}

__device__ __forceinline__ float wsum(float v){
  #pragma unroll
  for(int o=32;o>=1;o>>=1) v += __shfl_xor(v,o,64);
  return v;
}

// pe[p, 2i] = sin(p * exp(-2i*ln(10000)/48)), pe[p, 2i+1] = cos(...)
__device__ __forceinline__ float pe_val(int p, int j){
  int i = j >> 1;
  float f = expf(-0.19188209108283716f * (float)(2*i));
  float a = (float)p * f;
  return (j & 1) ? cosf(a) : sinf(a);
}

union F4H8 { float4 f4; __half2 h2[4]; };
union F2H4 { float2 f2; __half2 h2[2]; };

// dot of 48-float x (12 float4) with 48 fp16 weights (6 float4-chunks)
__device__ __forceinline__ float dot48h(const float4* x, const __half* w){
  const float4* w4=(const float4*)w;
  float a=0.f;
  #pragma unroll
  for(int c=0;c<6;c++){
    F4H8 u; u.f4=w4[c];
    float2 f0=__half22float2(u.h2[0]), f1=__half22float2(u.h2[1]);
    float2 f2=__half22float2(u.h2[2]), f3=__half22float2(u.h2[3]);
    float4 x0=x[2*c], x1=x[2*c+1];
    a += x0.x*f0.x + x0.y*f0.y + x0.z*f1.x + x0.w*f1.y
       + x1.x*f2.x + x1.y*f2.y + x1.z*f3.x + x1.w*f3.y;
  }
  return a;
}
// dot of 128-float x (32 float4) with 128 fp16 weights (16 chunks)
__device__ __forceinline__ float dot128h(const float4* x, const __half* w){
  const float4* w4=(const float4*)w;
  float a=0.f;
  #pragma unroll
  for(int c=0;c<16;c++){
    F4H8 u; u.f4=w4[c];
    float2 f0=__half22float2(u.h2[0]), f1=__half22float2(u.h2[1]);
    float2 f2=__half22float2(u.h2[2]), f3=__half22float2(u.h2[3]);
    float4 x0=x[2*c], x1=x[2*c+1];
    a += x0.x*f0.x + x0.y*f0.y + x0.z*f1.x + x0.w*f1.y
       + x1.x*f2.x + x1.y*f2.y + x1.z*f3.x + x1.w*f3.y;
  }
  return a;
}
__device__ __forceinline__ float dot12f(const float4* x, const float4* k){
  float a=0.f;
  #pragma unroll
  for(int u=0;u<3;u++){ float4 xx=x[u], kk=k[u];
    a+=xx.x*kk.x+xx.y*kk.y+xx.z*kk.z+xx.w*kk.w; }
  return a;
}

// ---------------- K1: embed + PE -> X0 (fp32) ----------------
__global__ void k_embed(const float* __restrict__ src, const float* __restrict__ in_w,
                        const float* __restrict__ in_b, float* __restrict__ X0){
  int idx = blockIdx.x*256 + threadIdx.x;
  if (idx >= kB*kS*kD) return;
  int j = idx % kD; int bs = idx / kD; int s = bs % kS;
  float v = (src[bs] * in_w[j] + in_b[j]) * 6.928203230275509f;
  X0[idx] = v + pe_val(s, j);
}

// ---------------- K2: encoder QKV projection (fp16 out), W^T in LDS ----------------
__global__ void __launch_bounds__(256) k_qkv(const float* __restrict__ X,
    const float* __restrict__ wq, const float* __restrict__ bq,
    const float* __restrict__ wk, const float* __restrict__ bk,
    const float* __restrict__ wv, const float* __restrict__ bv,
    __half* __restrict__ Q, __half* __restrict__ K, __half* __restrict__ V){
  __shared__ __align__(16) float W[3*2496];
  __shared__ __align__(16) float bias[3*kD];
  __shared__ __align__(16) float xt[32*kD];
  int tid = threadIdx.x;
  for (int i=tid;i<3*2304;i+=256){ int m=i/2304, e=i%2304, k=e/48, j=e%48;
    const float* w = (m==0)?wq:((m==1)?wk:wv);
    W[m*2496 + j*52 + k] = w[e]; }
  for (int i=tid;i<3*kD;i+=256){ int m=i/kD,e=i%kD;
    const float* w=(m==0)?bq:((m==1)?bk:bv); bias[i]=w[e]; }
  long row0 = (long)blockIdx.x*32;
  for (int i=tid;i<32*kD;i+=256) xt[i] = X[row0*kD + i];
  __syncthreads();
  int r = tid>>3, c0 = tid&7;
  float4 xr[12];
  const float4* xp=(const float4*)(xt + r*kD);
  #pragma unroll
  for(int u=0;u<12;u++) xr[u]=xp[u];
  for (int c=c0; c<3*kD; c+=8){
    int m=c/kD, j=c%kD;
    const float4* w4=(const float4*)(W + m*2496 + j*52);
    float acc = bias[m*kD+j];
    #pragma unroll
    for(int k=0;k<12;k++){ float4 xx=xr[k], ww=w4[k];
      acc+=xx.x*ww.x+xx.y*ww.y+xx.z*ww.z+xx.w*ww.w; }
    __half* o = (m==0)?Q:((m==1)?K:V);
    o[(row0+r)*kD+j]=__float2half(acc);
  }
}

// ---------------- K3: encoder attention — half2 K/V in LDS (2 reads/row) ----------------
__global__ void __launch_bounds__(256) k_attn(const __half* Q, const __half* __restrict__ K,
                       const __half* __restrict__ V, __half* O){
  int b = blockIdx.x / kNH, h = blockIdx.x % kNH;
  __shared__ __align__(16) __half2 Ks2[kS*8];   // row r at r*8: 6 half2 + 2 pad
  __shared__ __align__(16) __half2 Vs2[kS*8];
  int tid = threadIdx.x;
  long base = ((long)b*kS)*kD + h*kHD;
  for (int i=tid;i<kS*6;i+=256){ int r=i/6, u=i%6;
    Ks2[r*8+u] = *(const __half2*)(K + base + (long)r*kD + 2*u);
    Vs2[r*8+u] = *(const __half2*)(V + base + (long)r*kD + 2*u); }
  const float rs = 0.28867513459481287f;
  int q0 = tid, q1 = tid+256;
  float qa[kHD], qb[kHD];
  #pragma unroll
  for(int j=0;j<kHD;j++){
    qa[j]=__half2float(Q[base+(long)q0*kD+j])*rs;
    qb[j]=__half2float(Q[base+(long)q1*kD+j])*rs;
  }
  __syncthreads();
  float acc0[kHD], acc1[kHD];
  #pragma unroll
  for(int j=0;j<kHD;j++){ acc0[j]=0.f; acc1[j]=0.f; }
  float l0=0.f, l1=0.f;
  for(int k=0;k<kS;k++){
    F4H8 ku; ku.f4 = *(const float4*)(Ks2+k*8);
    F2H4 ku2; ku2.f2 = *(const float2*)(Ks2+k*8+4);
    float2 k0=__half22float2(ku.h2[0]), k1=__half22float2(ku.h2[1]);
    float2 k2=__half22float2(ku.h2[2]), k3=__half22float2(ku.h2[3]);
    float2 k4=__half22float2(ku2.h2[0]), k5=__half22float2(ku2.h2[1]);
    float kr[kHD]={k0.x,k0.y,k1.x,k1.y,k2.x,k2.y,k3.x,k3.y,k4.x,k4.y,k5.x,k5.y};
    float s0=0.f,s1=0.f;
    #pragma unroll
    for(int j=0;j<kHD;j++){ s0+=qa[j]*kr[j]; s1+=qb[j]*kr[j]; }
    float p0=__expf(s0), p1=__expf(s1);   // |s|<~42 << 88: exp-safe
    l0+=p0; l1+=p1;
    F4H8 vu; vu.f4 = *(const float4*)(Vs2+k*8);
    F2H4 vu2; vu2.f2 = *(const float2*)(Vs2+k*8+4);
    float2 v0=__half22float2(vu.h2[0]), v1=__half22float2(vu.h2[1]);
    float2 v2=__half22float2(vu.h2[2]), v3=__half22float2(vu.h2[3]);
    float2 v4=__half22float2(vu2.h2[0]), v5=__half22float2(vu2.h2[1]);
    float vr[kHD]={v0.x,v0.y,v1.x,v1.y,v2.x,v2.y,v3.x,v3.y,v4.x,v4.y,v5.x,v5.y};
    #pragma unroll
    for(int j=0;j<kHD;j++){ acc0[j]+=p0*vr[j]; acc1[j]+=p1*vr[j]; }
  }
  float i0=1.f/l0, i1=1.f/l1;
  #pragma unroll
  for(int j=0;j<kHD;j++){
    O[base+(long)q0*kD+j]=__float2half(acc0[j]*i0);
    O[base+(long)q1*kD+j]=__float2half(acc1[j]*i1);
  }
}

// ---------------- K4: o-proj + residual + LN (unchanged from R7) ----------------
__global__ void __launch_bounds__(256) k_oproj_ln(const float* __restrict__ Xres, const __half* __restrict__ O,
      const float* __restrict__ wo, const float* __restrict__ bo,
      const float* __restrict__ g, const float* __restrict__ bb,
      __half* __restrict__ Xout){
  __shared__ __align__(16) float W[kD*52];
  __shared__ float bsh[kD], gs[kD], bs2[kD];
  __shared__ __align__(16) float res[32*kD];
  __shared__ __align__(16) float ot[32*kD];
  __shared__ float mrow[32], rstd[32];
  int tid=threadIdx.x;
  for(int i=tid;i<kD*kD;i+=256){ int k=i/48, j=i%48; W[j*52+k]=wo[i]; }
  if(tid<kD){ bsh[tid]=bo[tid]; gs[tid]=g[tid]; bs2[tid]=bb[tid]; }
  long row0=(long)blockIdx.x*32;
  for(int i=tid;i<32*kD;i+=256) ot[i]=__half2float(O[row0*kD+i]);
  __syncthreads();
  int r=tid>>3, c0=tid&7;
  float4 orow[12];
  const float4* op=(const float4*)(ot + r*kD);
  #pragma unroll
  for(int u=0;u<12;u++) orow[u]=op[u];
  for(int j=c0;j<kD;j+=8){
    const float4* w4=(const float4*)(W+j*52);
    float acc=bsh[j];
    #pragma unroll
    for(int k=0;k<12;k++){ float4 xx=orow[k], ww=w4[k];
      acc+=xx.x*ww.x+xx.y*ww.y+xx.z*ww.z+xx.w*ww.w; }
    res[r*kD+j]=Xres[row0*kD + r*kD + j]+acc;
  }
  __syncthreads();
  if(tid<32){
    float s=0.f, s2=0.f;
    for(int j=0;j<kD;j++){ float v=res[tid*kD+j]; s+=v; s2+=v*v; }
    float m=s*(1.f/kD);
    mrow[tid]=m; rstd[tid]=rsqrtf(s2*(1.f/kD)-m*m+1e-5f);
  }
  __syncthreads();
  for(int i=tid;i<32*kD;i+=256){int r2=i/kD,j=i%kD;
    Xout[row0*kD+i]=__float2half((res[i]-mrow[r2])*rstd[r2]*gs[j]+bs2[j]); }
}

// ---------------- K5: FFN + residual + LN (unchanged from R7) ----------------
__global__ void __launch_bounds__(256) k_ffn_ln(const __half* __restrict__ Xin,
   const float* __restrict__ w1, const float* __restrict__ b1,
   const float* __restrict__ w2, const float* __restrict__ b2,
   const float* __restrict__ g, const float* __restrict__ bb,
   float* __restrict__ Xout){
  __shared__ __align__(16) float W1[kFF*52];
  __shared__ __align__(16) float W2[kD*132];
  __shared__ float b1s[kFF], b2s[kD], gs[kD], bs2[kD];
  __shared__ __align__(16) float xt[16*kD];
  __shared__ __align__(16) float h1v[16*kFF];
  __shared__ __align__(16) float res[16*kD];
  __shared__ float mrow[16], rstd[16];
  int tid=threadIdx.x;
  for(int i=tid;i<kD*kFF;i+=256){ int k=i/128, c=i%128; W1[c*52+k]=w1[i]; }
  for(int i=tid;i<kFF*kD;i+=256){ int u=i/48, j=i%48; W2[j*132+u]=w2[i]; }
  if(tid<kFF) b1s[tid]=b1[tid];
  if(tid<kD){ b2s[tid]=b2[tid]; gs[tid]=g[tid]; bs2[tid]=bb[tid]; }
  long row0=(long)blockIdx.x*16;
  for(int i=tid;i<16*kD;i+=256) xt[i]=__half2float(Xin[row0*kD+i]);
  __syncthreads();
  int r=tid>>4, c0=tid&15;
  {
    float4 xr[12];
    const float4* xp=(const float4*)(xt + r*kD);
    #pragma unroll
    for(int u=0;u<12;u++) xr[u]=xp[u];
    for(int c=c0;c<kFF;c+=16){
      const float4* w4=(const float4*)(W1+c*52);
      float acc=b1s[c];
      #pragma unroll
      for(int k=0;k<12;k++){ float4 xx=xr[k], ww=w4[k];
        acc+=xx.x*ww.x+xx.y*ww.y+xx.z*ww.z+xx.w*ww.w; }
      h1v[r*kFF+c]=fmaxf(acc,0.f);
    }
  }
  __syncthreads();
  {
    float4 hr[32];
    const float4* hp=(const float4*)(h1v + r*kFF);
    #pragma unroll
    for(int u=0;u<32;u++) hr[u]=hp[u];
    for(int j=c0;j<kD;j+=16){
      const float4* w4=(const float4*)(W2+j*132);
      float acc=b2s[j];
      #pragma unroll
      for(int k=0;k<32;k++){ float4 xx=hr[k], ww=w4[k];
        acc+=xx.x*ww.x+xx.y*ww.y+xx.z*ww.z+xx.w*ww.w; }
      res[r*kD+j]=xt[r*kD+j]+acc;
    }
  }
  __syncthreads();
  if(tid<16){
    float s=0.f, s2=0.f;
    for(int j=0;j<kD;j++){ float v=res[tid*kD+j]; s+=v; s2+=v*v; }
    float m=s*(1.f/kD);
    mrow[tid]=m; rstd[tid]=rsqrtf(s2*(1.f/kD)-m*m+1e-5f);
  }
  __syncthreads();
  for(int i=tid;i<16*kD;i+=256){int r2=i/kD,j=i%kD;
    Xout[row0*kD+i]=(res[i]-mrow[r2])*rstd[r2]*gs[j]+bs2[j]; }
}

// ---------------- K6: cross K/V projection, transposed fp16 out (unchanged) ----------------
__global__ void __launch_bounds__(256) k_ckv(const float* __restrict__ M,
    const float* __restrict__ wk, const float* __restrict__ bk,
    const float* __restrict__ wv, const float* __restrict__ bv,
    __half* __restrict__ Kc, __half* __restrict__ Vc){
  __shared__ __align__(16) float W[2*2496];
  __shared__ float bias[2*kD];
  __shared__ __align__(16) float xt[32*kD];
  int tid=threadIdx.x;
  for(int i=tid;i<2*2304;i+=256){ int m=i/2304, e=i%2304, k=e/48, j=e%48;
    W[m*2496 + j*52 + k] = (m?wv:wk)[e]; }
  for(int i=tid;i<2*kD;i+=256){ int m=i/kD,e=i%kD; bias[i]=(m?bv:bk)[e]; }
  long row0=(long)blockIdx.x*32;
  for(int i=tid;i<32*kD;i+=256) xt[i]=M[row0*kD+i];
  __syncthreads();
  int r=tid>>3, c0=tid&7;
  float4 xr[12];
  const float4* xp=(const float4*)(xt + r*kD);
  #pragma unroll
  for(int u=0;u<12;u++) xr[u]=xp[u];
  long gr=row0+r; long bb2=gr>>9; long s=gr&511;
  for(int c=c0;c<2*kD;c+=8){
    int m=c/kD, j=c%kD;
    const float4* w4=(const float4*)(W+m*2496+j*52);
    float acc=bias[m*kD+j];
    #pragma unroll
    for(int k=0;k<12;k++){ float4 xx=xr[k], ww=w4[k];
      acc+=xx.x*ww.x+xx.y*ww.y+xx.z*ww.z+xx.w*ww.w; }
    (m?Vc:Kc)[(bb2*kD+j)*kS+s]=__float2half(acc);
  }
}

// ---------------- K0: decoder weights -> padded FP16, column-major ----------------
// Wh halves: 6 mats 48 cols stride 56: swq@0 swk@2688 swv@5376 swo@8064 cwq@10752
// cwo@13440; w1 128 cols stride 56 @16128; w2 48 cols stride 136 @23296. Tot 29824.
__global__ void k_prep(const float* __restrict__ swq,const float* __restrict__ swk,
                       const float* __restrict__ swv,const float* __restrict__ swo,
                       const float* __restrict__ cwq,const float* __restrict__ cwo,
                       const float* __restrict__ w1,const float* __restrict__ w2,
                       __half* __restrict__ Wh){
  int idx=blockIdx.x*256+threadIdx.x;
  if(idx>=26112) return;
  if(idx<13824){
    int m=idx/2304, e=idx%2304, j=e/48, k=e%48;
    const float* w = (m==0)?swq:((m==1)?swk:((m==2)?swv:((m==3)?swo:((m==4)?cwq:cwo))));
    Wh[m*2688 + j*56 + k] = __float2half(w[k*48+j]);
  } else if(idx<19968){
    int e=idx-13824, c=e/48, k=e%48;
    Wh[16128 + c*56 + k] = __float2half(w1[k*128+c]);
  } else {
    int e=idx-19968, j=e/128, u=e%128;
    Wh[23296 + j*136 + u] = __float2half(w2[u*48+j]);
  }
}

// ---------------- K7: decoder — multi-wave pipelined step, KV-in-regs ----------------
struct DecP {
  const float *dec_start, *sbq, *sbk, *sbv, *sbo, *ln1g, *ln1b,
              *cbq, *cbo, *ln2g, *ln2b, *fb1, *fb2, *ln3g, *ln3b, *ow, *ob;
};

__global__ void __launch_bounds__(256,1) k_dec(const __half* __restrict__ KT,
    const __half* __restrict__ VT, const __half* __restrict__ Wg, DecP P,
    float* __restrict__ out){
  __shared__ __align__(16) __half Wl[29824];       // fp16 weights, 58.25 KB
  __shared__ __align__(16) float Kh[kNH*kT*kHD];   // per-head self-K cache, 12 KB
  __shared__ __align__(16) float Vh[kNH*kT*kHD];
  __shared__ __align__(16) float qS[kNH*16];
  __shared__ __align__(16) float xvS[kD], soS[kD], h1S[kD], h2S[kD], cqS[kD], covS[kD];
  __shared__ __align__(16) float f1S[kFF];
  int tid=threadIdx.x, b=blockIdx.x, wave=tid>>6, lane=tid&63;
  const float rs=0.28867513459481287f;

  for(int i=tid;i<29824/8;i+=256) ((float4*)Wl)[i]=((const float4*)Wg)[i];

  // per-lane constants
  float cur=0, c_bo=0,c_cbq=0,c_cbo=0,c_fb2=0;
  float g1=0,bb1=0,g2=0,bb2=0,g3=0,bb3=0,c_ow=0;
  float c_qkvb=0, c_fb1=0;
  if(wave==0 && lane<kD){
    cur=P.dec_start[lane];
    c_bo=P.sbo[lane]; c_cbq=P.cbq[lane]; c_cbo=P.cbo[lane]; c_fb2=P.fb2[lane];
    g1=P.ln1g[lane]; bb1=P.ln1b[lane];
    g2=P.ln2g[lane]; bb2=P.ln2b[lane];
    g3=P.ln3g[lane]; bb3=P.ln3b[lane];
    c_ow=P.ow[lane];
  }
  if(wave>=1 && lane<kD)
    c_qkvb = ((wave==1)?P.sbq:((wave==2)?P.sbk:P.sbv))[lane];
  if(wave<2) c_fb1=P.fb1[wave*64+lane];
  float c_ob=P.ob[0];

  // cross-attn K/V resident in registers: head = wave, 4 key-pairs per lane
  __half2 Kr[4][kHD], Vr[4][kHD];
  {
    const __half2* KTb=(const __half2*)KT + (long)b*kD*(kS/2);
    const __half2* VTb=(const __half2*)VT + (long)b*kD*(kS/2);
    #pragma unroll
    for(int i=0;i<4;i++){
      int pp=lane+64*i;
      #pragma unroll
      for(int u=0;u<kHD;u++){
        Kr[i][u]=KTb[(wave*kHD+u)*(kS/2)+pp];
        Vr[i][u]=VTb[(wave*kHD+u)*(kS/2)+pp];
      }
    }
  }
  __syncthreads();

  float h1=0, h2=0, xv=0;
  for(int t=0;t<kT;t++){
    // stage0: wave0 publishes x
    if(wave==0 && lane<kD){ xv=cur+pe_val(t,lane); xvS[lane]=xv; }
    __syncthreads();                                   // B0
    // stage1: waves 1..3 compute q/k/v (m = wave-1)
    if(wave>=1 && lane<kD){
      int m=wave-1;
      float a=c_qkvb+dot48h((const float4*)xvS, Wl + m*2688 + lane*56);
      int hh=lane/kHD, dd=lane%kHD;
      if(m==0) qS[hh*16+dd]=a;
      else if(m==1) Kh[(hh*kT+t)*kHD+dd]=a;
      else          Vh[(hh*kT+t)*kHD+dd]=a;
    }
    __syncthreads();                                   // B1
    // stage2: self-attn, head = wave, lane = key; probs in regs
    {
      float p=0.f, pv[kHD];
      #pragma unroll
      for(int u=0;u<kHD;u++) pv[u]=0.f;
      if(lane<=t){
        float s=dot12f((const float4*)(qS+wave*16),
                       (const float4*)(Kh+(wave*kT+lane)*kHD))*rs;
        p=__expf(s);
        const float4* vp=(const float4*)(Vh+(wave*kT+lane)*kHD);
        float4 v0=vp[0], v1=vp[1], v2=vp[2];
        float vr[kHD]={v0.x,v0.y,v0.z,v0.w,v1.x,v1.y,v1.z,v1.w,v2.x,v2.y,v2.z,v2.w};
        #pragma unroll
        for(int u=0;u<kHD;u++) pv[u]=p*vr[u];
      }
      float l=wsum(p);
      #pragma unroll
      for(int u=0;u<kHD;u++) pv[u]=wsum(pv[u]);
      if(lane==0){
        float inv=1.f/l;
        #pragma unroll
        for(int u=0;u<kHD;u++) soS[wave*kHD+u]=pv[u]*inv;
      }
    }
    __syncthreads();                                   // B2
    // stage3: wave0 — self o-proj + residual + LN1 + cross-q
    if(wave==0){
      float rr=0.f;
      if(lane<kD)
        rr=xv+c_bo+dot48h((const float4*)soS, Wl+8064+lane*56);
      float s1=wsum(rr), s2=wsum(rr*rr);
      float mean=s1*(1.f/48.f);
      float rstd=rsqrtf(s2*(1.f/48.f)-mean*mean+1e-5f);
      h1=0;
      if(lane<kD){ h1=(rr-mean)*rstd*g1+bb1; h1S[lane]=h1; }
      wsync();
      if(lane<kD)
        cqS[lane]=c_cbq+dot48h((const float4*)h1S, Wl+10752+lane*56);
    }
    __syncthreads();                                   // B3
    // stage4: cross-attn from registers, head = wave
    {
      const float4* q4=(const float4*)cqS;
      float4 qq0=q4[wave*3], qq1=q4[wave*3+1], qq2=q4[wave*3+2];
      float qh[kHD]={qq0.x,qq0.y,qq0.z,qq0.w,qq1.x,qq1.y,qq1.z,qq1.w,qq2.x,qq2.y,qq2.z,qq2.w};
      #pragma unroll
      for(int u=0;u<kHD;u++) qh[u]*=rs;
      float p[8], l=0.f;
      #pragma unroll
      for(int i=0;i<4;i++){
        float ax=0.f, ay=0.f;
        #pragma unroll
        for(int u=0;u<kHD;u++){ float2 kv=__half22float2(Kr[i][u]);
          ax+=qh[u]*kv.x; ay+=qh[u]*kv.y; }
        p[2*i]=__expf(ax); p[2*i+1]=__expf(ay);
        l+=p[2*i]+p[2*i+1];
      }
      l=wsum(l);
      float inv=1.f/l;
      float acc[kHD];
      #pragma unroll
      for(int u=0;u<kHD;u++) acc[u]=0.f;
      #pragma unroll
      for(int i=0;i<4;i++){
        #pragma unroll
        for(int u=0;u<kHD;u++){ float2 vv=__half22float2(Vr[i][u]);
          acc[u]+=p[2*i]*vv.x+p[2*i+1]*vv.y; }
      }
      #pragma unroll
      for(int u=0;u<kHD;u++) acc[u]=wsum(acc[u]);
      if(lane==0){
        #pragma unroll
        for(int u=0;u<kHD;u++) covS[wave*kHD+u]=acc[u]*inv;
      }
    }
    __syncthreads();                                   // B4
    // stage5: wave0 — cross o-proj + residual + LN2
    if(wave==0){
      float rr=0.f;
      if(lane<kD)
        rr=h1+c_cbo+dot48h((const float4*)covS, Wl+13440+lane*56);
      float s1=wsum(rr), s2=wsum(rr*rr);
      float mean=s1*(1.f/48.f);
      float rstd=rsqrtf(s2*(1.f/48.f)-mean*mean+1e-5f);
      h2=0;
      if(lane<kD){ h2=(rr-mean)*rstd*g2+bb2; h2S[lane]=h2; }
    }
    __syncthreads();                                   // B5
    // stage6: FFN1 on waves 0,1 (col = wave*64 + lane)
    if(wave<2){
      int col=wave*64+lane;
      float a=c_fb1+dot48h((const float4*)h2S, Wl+16128+col*56);
      f1S[col]=fmaxf(a,0.f);
    }
    __syncthreads();                                   // B6
    // stage7: wave0 — FFN2 + residual + LN3 + output; publish xv via cur for t+1
    if(wave==0){
      float rr=0.f;
      if(lane<kD)
        rr=h2+c_fb2+dot128h((const float4*)f1S, Wl+23296+lane*136);
      float s1=wsum(rr), s2=wsum(rr*rr);
      float mean=s1*(1.f/48.f);
      float rstd=rsqrtf(s2*(1.f/48.f)-mean*mean+1e-5f);
      float cv=0.f;
      if(lane<kD){ cv=(rr-mean)*rstd*g3+bb3; cur=cv; }
      float y=wsum(cv*c_ow);
      if(lane==0) out[b*kT+t]=y+c_ob;
    }
  }
}

extern "C" void kernel_launch(void* const* d_in, const int* in_sizes, int n_in,
                              void* d_out, int out_size, void* d_ws, size_t ws_size,
                              hipStream_t stream){
  // ws: Wh fp16 (reserve 65536 B), A fp32 NB, H1/H2/H3 fp16 NB each (~31.5 MiB).
  float* ws = (float*)d_ws;
  __half* Wh = (__half*)ws;
  const size_t NB = (size_t)kB*kS*kD;     // 3,145,728
  float*  A  = ws + 16384;
  __half* H1 = (__half*)(A + NB);
  __half* H2 = H1 + NB;
  __half* H3 = H2 + NB;

  k_embed<<<(kB*kS*kD+255)/256,256,0,stream>>>((const float*)d_in[0],(const float*)d_in[1],(const float*)d_in[2],A);
  k_qkv  <<<(kB*kS)/32,256,0,stream>>>(A,(const float*)d_in[4],(const float*)d_in[5],(const float*)d_in[6],
                                       (const float*)d_in[7],(const float*)d_in[8],(const float*)d_in[9],H1,H2,H3);
  k_attn <<<kB*kNH,256,0,stream>>>(H1,H2,H3,H1);
  k_oproj_ln<<<(kB*kS)/32,256,0,stream>>>(A,H1,(const float*)d_in[10],(const float*)d_in[11],
                                          (const float*)d_in[12],(const float*)d_in[13],H2);
  k_ffn_ln  <<<(kB*kS)/16,256,0,stream>>>(H2,(const float*)d_in[14],(const float*)d_in[15],(const float*)d_in[16],
                                          (const float*)d_in[17],(const float*)d_in[18],(const float*)d_in[19],A);
  k_ckv     <<<(kB*kS)/32,256,0,stream>>>(A,(const float*)d_in[32],(const float*)d_in[33],
                                          (const float*)d_in[34],(const float*)d_in[35],H1,H3);
  k_prep    <<<(26112+255)/256,256,0,stream>>>((const float*)d_in[20],(const float*)d_in[22],(const float*)d_in[24],
                                               (const float*)d_in[26],(const float*)d_in[30],(const float*)d_in[36],
                                               (const float*)d_in[40],(const float*)d_in[42],Wh);
  DecP P;
  P.dec_start=(const float*)d_in[3];
  P.sbq=(const float*)d_in[21]; P.sbk=(const float*)d_in[23]; P.sbv=(const float*)d_in[25]; P.sbo=(const float*)d_in[27];
  P.ln1g=(const float*)d_in[28]; P.ln1b=(const float*)d_in[29];
  P.cbq=(const float*)d_in[31]; P.cbo=(const float*)d_in[37];
  P.ln2g=(const float*)d_in[38]; P.ln2b=(const float*)d_in[39];
  P.fb1=(const float*)d_in[41]; P.fb2=(const float*)d_in[43];
  P.ln3g=(const float*)d_in[44]; P.ln3b=(const float*)d_in[45];
  P.ow=(const float*)d_in[46]; P.ob=(const float*)d_in[47];
  k_dec<<<kB,256,0,stream>>>(H1,H3,Wh,P,(float*)d_out);
}